// Round 8
// baseline (3655.426 us; speedup 1.0000x reference)
//
#include <hip/hip_runtime.h>

#define DD 300
#define KP 320   // padded K for pre-transposed weights

typedef __attribute__((ext_vector_type(8))) short short8v;   // 8 bf16 = 4 VGPR
typedef __attribute__((ext_vector_type(4))) float f32x4;

__device__ __forceinline__ float4 ld4(const float* p) { return *(const float4*)p; }

__device__ __forceinline__ unsigned short f2bf(float f) {
    unsigned int u = __float_as_uint(f);
    unsigned int r = (u + 0x7fffu + ((u >> 16) & 1u)) >> 16;   // RNE
    return (unsigned short)r;
}
__device__ __forceinline__ float bf2f(unsigned short b) {
    return __uint_as_float(((unsigned int)b) << 16);
}

// ---- manual OCP e4m3fn -----------------------------------------------------
__device__ __forceinline__ unsigned char f2e4(float f) {
    unsigned int u = __float_as_uint(f);
    unsigned int s = (u >> 24) & 0x80u;
    float a = __uint_as_float(u & 0x7fffffffu);
    if (a >= 448.f) return (unsigned char)(s | 0x7Eu);
    if (a < 0x1p-10f) return (unsigned char)s;
    int e = (int)((__float_as_uint(a) >> 23) & 0xFF) - 127;
    int q = (e >= -6) ? (e - 3) : -9;
    float scale = __uint_as_float((unsigned int)(127 - q) << 23);
    int m = __float2int_rn(a * scale);
    if (e >= -6) {
        if (m == 16) { m = 8; e += 1; }
        return (unsigned char)(s | ((unsigned int)(e + 7) << 3) | (unsigned int)(m - 8));
    } else {
        if (m == 8) return (unsigned char)(s | (1u << 3));
        return (unsigned char)(s | (unsigned int)m);
    }
}
__device__ __forceinline__ float e42f(unsigned char b) {
    unsigned int s = ((unsigned int)(b & 0x80u)) << 24;
    unsigned int ef = (b >> 3) & 0xFu, mf = b & 7u;
    float mag = (ef == 0) ? ((float)mf) * 0x1p-9f
                          : __uint_as_float(((ef + 120u) << 23) | (mf << 20));
    return __uint_as_float(__float_as_uint(mag) | s);
}

// ===========================================================================
// Weight prep: W[k][col] fp32 -> transposed split bf16 hi/lo [col][KP]
// (computed once; bit-identical to the per-block split it replaces)
// ===========================================================================
__global__ void prep_w(const float* __restrict__ W,
                       unsigned short* __restrict__ hi,
                       unsigned short* __restrict__ lo)
{
    int id = blockIdx.x * 256 + threadIdx.x;       // id = col*KP + k
    if (id >= DD * KP) return;
    int col = id / KP, k = id - col * KP;
    float v = (k < DD) ? W[(size_t)k * DD + col] : 0.f;
    unsigned short h = f2bf(v);
    hi[id] = h;
    lo[id] = f2bf(v - bf2f(h));
}

// ===========================================================================
// MFMA split-bf16 GEMM:  C[M,300] = f(A[M,300] @ B[300,300] + bias)
// B comes pre-transposed/pre-split (Bth/Btl, [col][KP] bf16).
// Split product: Ah*Bh + Ah*Bl + Al*Bh  (error ~1e-5, fp32-equivalent here)
// ===========================================================================
enum { MA_SUM2 = 0, MA_BF16 = 1, MA_NODE = 2, MA_EDGE = 3 };
enum { ME_RELU = 0, ME_BN = 1, ME_EMB = 2, ME_FP8 = 3 };

constexpr int TM = 128;
constexpr int TN = 128;
constexpr int TK = 32;
constexpr int KSTEPS = 10;   // 320 = KP
constexpr int APAD = 40;     // LDS row pitch in shorts (80 B: 20-dword stride)

template<int AM, int EM>
__launch_bounds__(256)
__global__ void mgemm(const unsigned short* __restrict__ Aa,
                      const unsigned short* __restrict__ Ab,
                      const unsigned short* __restrict__ Bth,
                      const unsigned short* __restrict__ Btl,
                      const float* __restrict__ bias,
                      const float* __restrict__ W1,
                      const float* __restrict__ b1,
                      const int* __restrict__ zidx,
                      const float* __restrict__ emb,
                      const int* __restrict__ permpos,
                      void* __restrict__ Cv,
                      double* __restrict__ bnsum, double* __restrict__ bnsq,
                      int M)
{
    constexpr bool SPLITA = (AM != MA_BF16);
    __shared__ unsigned short sAh[TM * APAD];
    __shared__ unsigned short sBh[TN * APAD];
    __shared__ unsigned short sBl[TN * APAD];
    __shared__ unsigned short sAl[SPLITA ? TM * APAD : 64];

    const int t    = threadIdx.x;
    const int col0 = blockIdx.x * TN;
    const int row0 = blockIdx.y * TM;
    const int lane = t & 63;
    const int wid  = t >> 6;
    const int wr   = wid >> 1;            // wave row (64 rows)
    const int wc   = wid & 1;             // wave col (64 cols)
    const int lr   = lane & 15;
    const int lk   = lane >> 4;           // 0..3

    // staging assignment (A and B use the same pattern: row = t>>1, khalf = t&1)
    const int arow = t >> 1;              // 0..127
    const int akq  = (t & 1) * 16;        // 0 / 16 (k offset)

    const int ga = row0 + arow;
    const int gbcol = col0 + arow;        // B: staged column
    float f0 = 0.f, f1 = 0.f, f2 = 0.f;
    if (AM == MA_NODE && ga < M) {
        f0 = ((const float*)Aa)[ga]; f1 = ((const float*)Ab)[ga];
    }
    if (AM == MA_EDGE && ga < M) {
        const float* Af = (const float*)Aa;
        f0 = Af[(size_t)ga * 3 + 0];
        f1 = Af[(size_t)ga * 3 + 1];
        f2 = Af[(size_t)ga * 3 + 2];
    }

    f32x4 acc[4][4];
#pragma unroll
    for (int i = 0; i < 4; ++i)
#pragma unroll
        for (int j = 0; j < 4; ++j) acc[i][j] = (f32x4){0.f, 0.f, 0.f, 0.f};

    for (int ks = 0; ks < KSTEPS; ++ks) {
        const int k0 = ks * TK;
        __syncthreads();

        // ---- stage A: rows 0..127, k = k0+akq .. +15 ----
        if (AM == MA_BF16) {
#pragma unroll
            for (int q = 0; q < 4; ++q) {
                const int k = k0 + akq + q * 4;
                ushort4 u = make_ushort4(0, 0, 0, 0);
                if (ga < M && k < DD) u = *(const ushort4*)(Aa + (size_t)ga * DD + k);
                *(ushort4*)&sAh[arow * APAD + akq + q * 4] = u;
            }
        } else {
            float v[16];
#pragma unroll
            for (int q = 0; q < 4; ++q) {
                const int k = k0 + akq + q * 4;
                if (AM == MA_SUM2) {
                    if (ga < M && k < DD) {
                        ushort4 ua = *(const ushort4*)(Aa + (size_t)ga * DD + k);
                        ushort4 ub = *(const ushort4*)(Ab + (size_t)ga * DD + k);
                        v[q*4+0] = bf2f(ua.x) + bf2f(ub.x);
                        v[q*4+1] = bf2f(ua.y) + bf2f(ub.y);
                        v[q*4+2] = bf2f(ua.z) + bf2f(ub.z);
                        v[q*4+3] = bf2f(ua.w) + bf2f(ub.w);
                    } else {
                        v[q*4+0] = v[q*4+1] = v[q*4+2] = v[q*4+3] = 0.f;
                    }
                } else {  // NODE / EDGE: relu(feats @ W1 + b1) on the fly
                    if (ga < M && k < DD) {
                        float4 w0 = ld4(W1 + k);
                        float4 w1 = ld4(W1 + DD + k);
                        float4 bb = ld4(b1 + k);
                        if (AM == MA_NODE) {
                            v[q*4+0] = fmaxf(fmaf(f0, w0.x, fmaf(f1, w1.x, bb.x)), 0.f);
                            v[q*4+1] = fmaxf(fmaf(f0, w0.y, fmaf(f1, w1.y, bb.y)), 0.f);
                            v[q*4+2] = fmaxf(fmaf(f0, w0.z, fmaf(f1, w1.z, bb.z)), 0.f);
                            v[q*4+3] = fmaxf(fmaf(f0, w0.w, fmaf(f1, w1.w, bb.w)), 0.f);
                        } else {
                            float4 w2 = ld4(W1 + 2 * DD + k);
                            v[q*4+0] = fmaxf(f0*w0.x + f1*w1.x + f2*w2.x + bb.x, 0.f);
                            v[q*4+1] = fmaxf(f0*w0.y + f1*w1.y + f2*w2.y + bb.y, 0.f);
                            v[q*4+2] = fmaxf(f0*w0.z + f1*w1.z + f2*w2.z + bb.z, 0.f);
                            v[q*4+3] = fmaxf(f0*w0.w + f1*w1.w + f2*w2.w + bb.w, 0.f);
                        }
                    } else {
                        v[q*4+0] = v[q*4+1] = v[q*4+2] = v[q*4+3] = 0.f;
                    }
                }
            }
#pragma unroll
            for (int q = 0; q < 4; ++q) {
                ushort4 hi, lo;
                hi.x = f2bf(v[q*4+0]); lo.x = f2bf(v[q*4+0] - bf2f(hi.x));
                hi.y = f2bf(v[q*4+1]); lo.y = f2bf(v[q*4+1] - bf2f(hi.y));
                hi.z = f2bf(v[q*4+2]); lo.z = f2bf(v[q*4+2] - bf2f(hi.z));
                hi.w = f2bf(v[q*4+3]); lo.w = f2bf(v[q*4+3] - bf2f(hi.w));
                *(ushort4*)&sAh[arow * APAD + akq + q * 4] = hi;
                if constexpr (SPLITA)
                    *(ushort4*)&sAl[arow * APAD + akq + q * 4] = lo;
            }
        }

        // ---- stage B: pure copy from pre-transposed split weights ----
        // same write pattern as A (row-stride 20 dwords: conflict-light)
#pragma unroll
        for (int q = 0; q < 4; ++q) {
            const int k = k0 + akq + q * 4;        // k < KP always
            ushort4 hv = make_ushort4(0, 0, 0, 0), lv = hv;
            if (gbcol < DD) {
                hv = *(const ushort4*)(Bth + (size_t)gbcol * KP + k);
                lv = *(const ushort4*)(Btl + (size_t)gbcol * KP + k);
            }
            *(ushort4*)&sBh[arow * APAD + akq + q * 4] = hv;
            *(ushort4*)&sBl[arow * APAD + akq + q * 4] = lv;
        }
        __syncthreads();

        // ---- fragments + MFMA ----
        short8v aH[4], aL[4], bH[4], bL[4];
#pragma unroll
        for (int f = 0; f < 4; ++f) {
            aH[f] = *(const short8v*)&sAh[(wr * 64 + f * 16 + lr) * APAD + lk * 8];
            bH[f] = *(const short8v*)&sBh[(wc * 64 + f * 16 + lr) * APAD + lk * 8];
            bL[f] = *(const short8v*)&sBl[(wc * 64 + f * 16 + lr) * APAD + lk * 8];
            if constexpr (SPLITA)
                aL[f] = *(const short8v*)&sAl[(wr * 64 + f * 16 + lr) * APAD + lk * 8];
        }
#pragma unroll
        for (int fi = 0; fi < 4; ++fi)
#pragma unroll
            for (int fj = 0; fj < 4; ++fj) {
                acc[fi][fj] = __builtin_amdgcn_mfma_f32_16x16x32_bf16(aH[fi], bH[fj], acc[fi][fj], 0, 0, 0);
                acc[fi][fj] = __builtin_amdgcn_mfma_f32_16x16x32_bf16(aH[fi], bL[fj], acc[fi][fj], 0, 0, 0);
                if constexpr (SPLITA)
                    acc[fi][fj] = __builtin_amdgcn_mfma_f32_16x16x32_bf16(aL[fi], bH[fj], acc[fi][fj], 0, 0, 0);
            }
    }

    // ---- epilogue: C row = row0+wr*64+fi*16+lk*4+i, col = col0+wc*64+fj*16+lr
    float csum[4], csq[4];
#pragma unroll
    for (int j = 0; j < 4; ++j) { csum[j] = 0.f; csq[j] = 0.f; }

#pragma unroll
    for (int fi = 0; fi < 4; ++fi) {
#pragma unroll
        for (int i = 0; i < 4; ++i) {
            const int r = row0 + wr * 64 + fi * 16 + lk * 4 + i;
            if (r < M) {
                int zr = 0, pr = 0;
                if (EM == ME_EMB) zr = zidx[r];
                if (EM == ME_FP8) pr = permpos[r];
#pragma unroll
                for (int fj = 0; fj < 4; ++fj) {
                    const int c = col0 + wc * 64 + fj * 16 + lr;
                    if (c < DD) {
                        float v = acc[fi][fj][i] + bias[c];
                        if (EM == ME_RELU) v = fmaxf(v, 0.f);
                        if (EM == ME_EMB)  v += emb[(size_t)zr * DD + c];
                        if (EM == ME_FP8)
                            ((unsigned char*)Cv)[(size_t)pr * DD + c] = f2e4(v);
                        else
                            ((unsigned short*)Cv)[(size_t)r * DD + c] = f2bf(v);
                        if (EM == ME_BN) { csum[fj] += v; csq[fj] += v * v; }
                    }
                }
            }
        }
    }

    if (EM == ME_BN) {
        // Per-column stats: shuffle-reduce lanes {l,l^16,l^32,l^48}, then
        // combine wave-rows via sRed[2][TN] (row=wr, col=wc*64+fj*16+lr).
#pragma unroll
        for (int fj = 0; fj < 4; ++fj) {
            csum[fj] += __shfl_xor(csum[fj], 16);
            csum[fj] += __shfl_xor(csum[fj], 32);
            csq[fj]  += __shfl_xor(csq[fj], 16);
            csq[fj]  += __shfl_xor(csq[fj], 32);
        }
        float* sRed = (float*)sAh;   // 2*128 floats, tiles are dead
        __syncthreads();
        if (lk == 0) {
#pragma unroll
            for (int fj = 0; fj < 4; ++fj)
                sRed[wr * TN + wc * 64 + fj * 16 + lr] = csum[fj];
        }
        __syncthreads();
        if (t < TN) {
            float s = sRed[t] + sRed[TN + t];
            const int c = col0 + t;
            if (c < DD) unsafeAtomicAdd(&bnsum[c], (double)s);
        }
        __syncthreads();
        if (lk == 0) {
#pragma unroll
            for (int fj = 0; fj < 4; ++fj)
                sRed[wr * TN + wc * 64 + fj * 16 + lr] = csq[fj];
        }
        __syncthreads();
        if (t < TN) {
            float s = sRed[t] + sRed[TN + t];
            const int c = col0 + t;
            if (c < DD) unsafeAtomicAdd(&bnsq[c], (double)s);
        }
    }
}

// ===========================================================================
// fp32 VALU GEMM kept only for the tiny final projection (G=4096)
// ===========================================================================
constexpr int GBM = 128;
constexpr int GBN = 128;
constexpr int GBK = 8;
constexpr int KPAD = 304;

__launch_bounds__(256)
__global__ void gemm_final(const float* __restrict__ Aa, const float* __restrict__ Bw,
                           const float* __restrict__ bias, float* __restrict__ C, int M)
{
    __shared__ float smem[2 * GBK * GBM];
    float* As = smem;
    float* Bs = smem + GBK * GBM;

    const int t    = threadIdx.x;
    const int tx   = t & 15;
    const int ty   = t >> 4;
    const int col0 = blockIdx.x * GBN;
    const int row0 = blockIdx.y * GBM;
    const int arow = t >> 1;
    const int akq  = (t & 1) << 2;
    const int brow = t >> 5;
    const int bnq  = (t & 31) << 2;
    const int ga   = row0 + arow;
    const int gb   = col0 + bnq;

    float acc[8][8];
#pragma unroll
    for (int i = 0; i < 8; ++i)
#pragma unroll
        for (int j = 0; j < 8; ++j) acc[i][j] = 0.f;

    for (int k0 = 0; k0 < KPAD; k0 += GBK) {
        float4 av = make_float4(0.f, 0.f, 0.f, 0.f);
        const int ka = k0 + akq;
        if (ga < M && ka < DD) av = ld4(Aa + (size_t)ga * DD + ka);
        As[(akq + 0) * GBM + arow] = av.x;
        As[(akq + 1) * GBM + arow] = av.y;
        As[(akq + 2) * GBM + arow] = av.z;
        As[(akq + 3) * GBM + arow] = av.w;

        float4 bv = make_float4(0.f, 0.f, 0.f, 0.f);
        const int kb = k0 + brow;
        if (kb < DD && gb < DD) bv = ld4(Bw + (size_t)kb * DD + gb);
        *(float4*)(Bs + brow * GBN + bnq) = bv;

        __syncthreads();
#pragma unroll
        for (int kk = 0; kk < GBK; ++kk) {
            float a[8], b[8];
            *(float4*)&a[0] = *(const float4*)(As + kk * GBM + 8 * ty);
            *(float4*)&a[4] = *(const float4*)(As + kk * GBM + 8 * ty + 4);
            *(float4*)&b[0] = *(const float4*)(Bs + kk * GBN + 8 * tx);
            *(float4*)&b[4] = *(const float4*)(Bs + kk * GBN + 8 * tx + 4);
#pragma unroll
            for (int i = 0; i < 8; ++i)
#pragma unroll
                for (int j = 0; j < 8; ++j)
                    acc[i][j] = fmaf(a[i], b[j], acc[i][j]);
        }
        __syncthreads();
    }

#pragma unroll
    for (int i = 0; i < 8; ++i) {
        const int r = row0 + 8 * ty + i;
        if (r < M) {
#pragma unroll
            for (int jq = 0; jq < 2; ++jq) {
                const int c = col0 + 8 * tx + 4 * jq;
                if (c < DD) {
                    float4 bb = ld4(bias + c);
                    *(float4*)(C + (size_t)r * DD + c) = make_float4(
                        acc[i][4*jq+0] + bb.x, acc[i][4*jq+1] + bb.y,
                        acc[i][4*jq+2] + bb.z, acc[i][4*jq+3] + bb.w);
                }
            }
        }
    }
}

// ===========================================================================
// CSR build
// ===========================================================================
__global__ void deg_kernel(const int* __restrict__ dst, int* __restrict__ deg, int E)
{
    int e = blockIdx.x * 256 + threadIdx.x;
    if (e < E) atomicAdd(&deg[dst[e]], 1);
}

__global__ void scan1(const int* __restrict__ deg, int* __restrict__ out,
                      int* __restrict__ bsum, int n)
{
    __shared__ int sh[256];
    const int t = threadIdx.x;
    const int base = blockIdx.x * 1024 + t * 4;
    int v0 = (base + 0 < n) ? deg[base + 0] : 0;
    int v1 = (base + 1 < n) ? deg[base + 1] : 0;
    int v2 = (base + 2 < n) ? deg[base + 2] : 0;
    int v3 = (base + 3 < n) ? deg[base + 3] : 0;
    const int s = v0 + v1 + v2 + v3;
    sh[t] = s;
    __syncthreads();
    for (int off = 1; off < 256; off <<= 1) {
        int x = (t >= off) ? sh[t - off] : 0;
        __syncthreads();
        sh[t] += x;
        __syncthreads();
    }
    int ex = sh[t] - s;
    if (base + 0 < n) out[base + 0] = ex; ex += v0;
    if (base + 1 < n) out[base + 1] = ex; ex += v1;
    if (base + 2 < n) out[base + 2] = ex; ex += v2;
    if (base + 3 < n) out[base + 3] = ex;
    if (t == 255) bsum[blockIdx.x] = sh[255];
}

__global__ void scan2(int* __restrict__ bsum, int nb, int* __restrict__ offs, int n, int E)
{
    __shared__ int sh[256];
    const int t = threadIdx.x;
    const int v = (t < nb) ? bsum[t] : 0;
    sh[t] = v;
    __syncthreads();
    for (int off = 1; off < 256; off <<= 1) {
        int x = (t >= off) ? sh[t - off] : 0;
        __syncthreads();
        sh[t] += x;
        __syncthreads();
    }
    if (t < nb) bsum[t] = sh[t] - v;
    if (t == 0) offs[n] = E;
}

__global__ void scan3(int* __restrict__ offs, const int* __restrict__ bsum,
                      int* __restrict__ cursor, int n)
{
    int i = blockIdx.x * 256 + threadIdx.x;
    if (i < n) {
        int v = offs[i] + bsum[i >> 10];
        offs[i] = v;
        cursor[i] = v;
    }
}

// entries: src only; permpos[e] = CSR slot so ebuf can be written permuted
__global__ void fill_kernel(const int* __restrict__ src, const int* __restrict__ dst,
                            int* __restrict__ cursor, int* __restrict__ esrc,
                            int* __restrict__ permpos, int E)
{
    int e = blockIdx.x * 256 + threadIdx.x;
    if (e < E) {
        int d = dst[e];
        int pos = atomicAdd(&cursor[d], 1);
        esrc[pos] = src[e];
        permpos[e] = pos;
    }
}

// ===========================================================================
// agg[i] = sum_in relu(h[src] + e[slot]);  4 nodes/block (1 wave each)
// ===========================================================================
__global__ void agg_kernel(const unsigned short* __restrict__ h,
                           const unsigned char* __restrict__ e,
                           const int* __restrict__ esrc, const int* __restrict__ offs,
                           unsigned short* __restrict__ agg, int N)
{
    const int node = blockIdx.x * 4 + (threadIdx.x >> 6);
    if (node >= N) return;
    const int lane = threadIdx.x & 63;
    const int beg = offs[node], end = offs[node + 1];
    for (int q = lane; q < 75; q += 64) {
        float4 s = make_float4(0.f, 0.f, 0.f, 0.f);
        for (int p = beg; p < end; ++p) {
            const int src = esrc[p];
            ushort4 hu = *(const ushort4*)(h + (size_t)src * DD + 4 * q);
            unsigned int eu = *(const unsigned int*)(e + (size_t)p * DD + 4 * q);
            s.x += fmaxf(bf2f(hu.x) + e42f((unsigned char)(eu & 0xFF)), 0.f);
            s.y += fmaxf(bf2f(hu.y) + e42f((unsigned char)((eu >> 8) & 0xFF)), 0.f);
            s.z += fmaxf(bf2f(hu.z) + e42f((unsigned char)((eu >> 16) & 0xFF)), 0.f);
            s.w += fmaxf(bf2f(hu.w) + e42f((unsigned char)(eu >> 24)), 0.f);
        }
        *(ushort4*)(agg + (size_t)node * DD + 4 * q) =
            make_ushort4(f2bf(s.x), f2bf(s.y), f2bf(s.z), f2bf(s.w));
    }
}

// ===========================================================================
// BatchNorm finalize + apply
// ===========================================================================
__global__ void bn_fin(const double* __restrict__ bnsum, const double* __restrict__ bnsq,
                       const float* __restrict__ gamma, const float* __restrict__ beta,
                       float* __restrict__ scale, float* __restrict__ shift, double invN)
{
    const int c = threadIdx.x;
    if (c < DD) {
        double mu = bnsum[c] * invN;
        double var = bnsq[c] * invN - mu * mu;
        double inv = 1.0 / sqrt(var + 1e-5);
        double g = (double)gamma[c];
        scale[c] = (float)(g * inv);
        shift[c] = (float)((double)beta[c] - mu * inv * g);
    }
}

__global__ void bn_apply(const unsigned short* __restrict__ h2,
                         const float* __restrict__ scale, const float* __restrict__ shift,
                         unsigned short* __restrict__ h, int total4)
{
    int idx = blockIdx.x * 256 + threadIdx.x;
    if (idx >= total4) return;
    int q = idx % 75;
    ushort4 v4 = ((const ushort4*)h2)[idx];
    float4 sc = ld4(scale + 4 * q);
    float4 sh = ld4(shift + 4 * q);
    float r0 = fmaxf(fmaf(bf2f(v4.x), sc.x, sh.x), 0.f);
    float r1 = fmaxf(fmaf(bf2f(v4.y), sc.y, sh.y), 0.f);
    float r2 = fmaxf(fmaf(bf2f(v4.z), sc.z, sh.z), 0.f);
    float r3 = fmaxf(fmaf(bf2f(v4.w), sc.w, sh.w), 0.f);
    ((ushort4*)h)[idx] = make_ushort4(f2bf(r0), f2bf(r1), f2bf(r2), f2bf(r3));
}

// ===========================================================================
// Per-graph mean pooling
// ===========================================================================
__global__ void pool_kernel(const unsigned short* __restrict__ h, const int* __restrict__ batch,
                            float* __restrict__ pooled, int N)
{
    const int g = blockIdx.x;
    __shared__ int sb[2];
    if (threadIdx.x == 0) {
        int lo = 0, hi = N;
        while (lo < hi) { int m = (lo + hi) >> 1; if (batch[m] < g) lo = m + 1; else hi = m; }
        sb[0] = lo;
        lo = 0; hi = N;
        while (lo < hi) { int m = (lo + hi) >> 1; if (batch[m] < g + 1) lo = m + 1; else hi = m; }
        sb[1] = lo;
    }
    __syncthreads();
    const int beg = sb[0], end = sb[1];
    const float cnt = (float)(end - beg);
    for (int d = threadIdx.x; d < DD; d += 256) {
        float s = 0.f;
        for (int i = beg; i < end; ++i) s += bf2f(h[(size_t)i * DD + d]);
        pooled[(size_t)g * DD + d] = (end > beg) ? (s / cnt) : 0.f;
    }
}

__global__ void diag_fill(float* __restrict__ out, int n, float v)
{
    int i = blockIdx.x * 256 + threadIdx.x;
    if (i < n) out[i] = v;
}

// ===========================================================================
extern "C" void kernel_launch(void* const* d_in, const int* in_sizes, int n_in,
                              void* d_out, int out_size, void* d_ws, size_t ws_size,
                              hipStream_t stream)
{
    const int N = in_sizes[0];
    const int E = in_sizes[3] / 2;
    const int G = out_size / DD;

    const int*   z     = (const int*)d_in[0];
    const float* chir  = (const float*)d_in[1];
    const float* fc    = (const float*)d_in[2];
    const int*   eidx  = (const int*)d_in[3];
    const float* eattr = (const float*)d_in[4];
    const int*   batch = (const int*)d_in[5];
    const float* aemb  = (const float*)d_in[7];
    const float* nW1   = (const float*)d_in[8];
    const float* nb1   = (const float*)d_in[9];
    const float* nW2   = (const float*)d_in[10];
    const float* nb2   = (const float*)d_in[11];
    const float* eW1   = (const float*)d_in[12];
    const float* eb1   = (const float*)d_in[13];
    const float* eW2   = (const float*)d_in[14];
    const float* eb2   = (const float*)d_in[15];
    const float* mW1   = (const float*)d_in[16];
    const float* mb1   = (const float*)d_in[17];
    const float* mW2   = (const float*)d_in[18];
    const float* mb2   = (const float*)d_in[19];
    const float* gamma = (const float*)d_in[20];
    const float* beta  = (const float*)d_in[21];
    const float* pW    = (const float*)d_in[22];
    const float* pb    = (const float*)d_in[23];
    float* out = (float*)d_out;

    size_t base = 0;
    auto A = [&](size_t b) -> size_t {
        size_t r = base; base += (b + 255) & ~(size_t)255; return r;
    };
    const size_t o_h    = A((size_t)N * DD * 2);   // h bf16
    const size_t o_t    = A((size_t)N * DD * 2);   // tbuf bf16 (pooled fp32 alias)
    const size_t o_g    = A((size_t)N * DD * 2);   // agg / h2 bf16
    const size_t o_bns  = A(DD * 8);
    const size_t o_bnq  = A(DD * 8);
    const size_t o_scl  = A(DD * 4);
    const size_t o_shf  = A(DD * 4);
    const size_t o_offs = A((size_t)(N + 1) * 4);
    const size_t o_cur  = A((size_t)N * 4);
    const size_t o_bsum = A(1024 * 4);
    const size_t o_src  = A((size_t)E * 4);
    const size_t o_perm = A((size_t)E * 4);
    const size_t o_wt   = A((size_t)12 * 2 * DD * KP * 2);  // 12 matrices, hi+lo
    const size_t o_e    = A((size_t)E * DD * 1);   // ebuf fp8, CSR-permuted
    const size_t need = base;

    if (ws_size < need) {
        diag_fill<<<(out_size + 255) / 256, 256, 0, stream>>>(
            out, out_size, 10000.f + (float)(ws_size >> 20));
        return;
    }

    char* w = (char*)d_ws;
    unsigned short* h      = (unsigned short*)(w + o_h);
    unsigned short* tbuf   = (unsigned short*)(w + o_t);
    unsigned short* aggh2  = (unsigned short*)(w + o_g);
    double*         bnsum  = (double*)(w + o_bns);
    double*         bnsq   = (double*)(w + o_bnq);
    float*          scl    = (float*)(w + o_scl);
    float*          shf    = (float*)(w + o_shf);
    int*            offs   = (int*)(w + o_offs);
    int*            cursor = (int*)(w + o_cur);
    int*            bsum   = (int*)(w + o_bsum);
    int*            esrc   = (int*)(w + o_src);
    int*            permpos= (int*)(w + o_perm);
    unsigned short* wt     = (unsigned short*)(w + o_wt);
    unsigned char*  ebuf   = (unsigned char*)(w + o_e);
    float*          pooled = (float*)tbuf;

    // weight slots: m=0 nW2, m=1 eW2, m=2+l mW1[l], m=7+l mW2[l]
    auto wHI = [&](int m) { return wt + (size_t)m * 2 * DD * KP; };
    auto wLO = [&](int m) { return wt + (size_t)m * 2 * DD * KP + DD * KP; };

    const int* srcI = eidx;
    const int* dstI = eidx + E;

    // ---- weight prep (once per launch; cheap) ----
    const int wblocks = (DD * KP + 255) / 256;
    prep_w<<<wblocks, 256, 0, stream>>>(nW2, wHI(0), wLO(0));
    prep_w<<<wblocks, 256, 0, stream>>>(eW2, wHI(1), wLO(1));
    for (int l = 0; l < 5; ++l) {
        prep_w<<<wblocks, 256, 0, stream>>>(mW1 + (size_t)l * DD * DD, wHI(2 + l), wLO(2 + l));
        prep_w<<<wblocks, 256, 0, stream>>>(mW2 + (size_t)l * DD * DD, wHI(7 + l), wLO(7 + l));
    }

    // ---- CSR of incoming edges ----
    hipMemsetAsync(cursor, 0, (size_t)N * 4, stream);
    deg_kernel<<<(E + 255) / 256, 256, 0, stream>>>(dstI, cursor, E);
    const int nb = (N + 1023) / 1024;
    scan1<<<nb, 256, 0, stream>>>(cursor, offs, bsum, N);
    scan2<<<1, 256, 0, stream>>>(bsum, nb, offs, N, E);
    scan3<<<(N + 255) / 256, 256, 0, stream>>>(offs, bsum, cursor, N);
    fill_kernel<<<(E + 255) / 256, 256, 0, stream>>>(srcI, dstI, cursor, esrc, permpos, E);

    const dim3 gN(3, (N + TM - 1) / TM);
    const dim3 gE(3, (E + TM - 1) / TM);
    const dim3 gG(3, (G + GBM - 1) / GBM);

    // ---- encoders (MFMA) ----
    mgemm<MA_NODE, ME_EMB><<<gN, 256, 0, stream>>>(
        (const unsigned short*)chir, (const unsigned short*)fc, wHI(0), wLO(0), nb2,
        nW1, nb1, z, aemb, nullptr, h, nullptr, nullptr, N);
    mgemm<MA_EDGE, ME_FP8><<<gE, 256, 0, stream>>>(
        (const unsigned short*)eattr, nullptr, wHI(1), wLO(1), eb2,
        eW1, eb1, nullptr, nullptr, permpos, ebuf, nullptr, nullptr, E);

    // ---- 5 GINE layers ----
    for (int l = 0; l < 5; ++l) {
        agg_kernel<<<(N + 3) / 4, 256, 0, stream>>>(h, ebuf, esrc, offs, aggh2, N);
        mgemm<MA_SUM2, ME_RELU><<<gN, 256, 0, stream>>>(
            h, aggh2, wHI(2 + l), wLO(2 + l), mb1 + l * DD,
            nullptr, nullptr, nullptr, nullptr, nullptr, tbuf, nullptr, nullptr, N);
        hipMemsetAsync(bnsum, 0, DD * 8, stream);
        hipMemsetAsync(bnsq, 0, DD * 8, stream);
        mgemm<MA_BF16, ME_BN><<<gN, 256, 0, stream>>>(
            tbuf, nullptr, wHI(7 + l), wLO(7 + l), mb2 + l * DD,
            nullptr, nullptr, nullptr, nullptr, nullptr, aggh2, bnsum, bnsq, N);
        bn_fin<<<1, 320, 0, stream>>>(bnsum, bnsq, gamma + l * DD, beta + l * DD,
                                      scl, shf, 1.0 / (double)N);
        const int tot4 = N * 75;
        bn_apply<<<(tot4 + 255) / 256, 256, 0, stream>>>(aggh2, scl, shf, h, tot4);
    }

    // ---- pooling + final projection ----
    pool_kernel<<<G, 256, 0, stream>>>(h, batch, pooled, N);
    gemm_final<<<gG, 256, 0, stream>>>(pooled, pW, pb, out, G);
}

// Round 9
// 3228.968 us; speedup vs baseline: 1.1321x; 1.1321x over previous
//
#include <hip/hip_runtime.h>

#define DD 300
#define KP 320    // padded K for pre-transposed weights
#define WTR 384   // weight rows padded to 3*128 (no guard needed in DMA staging)

typedef __attribute__((ext_vector_type(8))) short short8v;   // 8 bf16 = 4 VGPR
typedef __attribute__((ext_vector_type(4))) float f32x4;

__device__ __forceinline__ float4 ld4(const float* p) { return *(const float4*)p; }

__device__ __forceinline__ unsigned short f2bf(float f) {
    unsigned int u = __float_as_uint(f);
    unsigned int r = (u + 0x7fffu + ((u >> 16) & 1u)) >> 16;   // RNE
    return (unsigned short)r;
}
__device__ __forceinline__ float bf2f(unsigned short b) {
    return __uint_as_float(((unsigned int)b) << 16);
}

// async global->LDS, 16 B per lane; LDS dest = base + lane*16
__device__ __forceinline__ void gload16(const void* g, void* l) {
    __builtin_amdgcn_global_load_lds(
        (const __attribute__((address_space(1))) unsigned int*)g,
        (__attribute__((address_space(3))) unsigned int*)l, 16, 0, 0);
}

// ---- manual OCP e4m3fn -----------------------------------------------------
__device__ __forceinline__ unsigned char f2e4(float f) {
    unsigned int u = __float_as_uint(f);
    unsigned int s = (u >> 24) & 0x80u;
    float a = __uint_as_float(u & 0x7fffffffu);
    if (a >= 448.f) return (unsigned char)(s | 0x7Eu);
    if (a < 0x1p-10f) return (unsigned char)s;
    int e = (int)((__float_as_uint(a) >> 23) & 0xFF) - 127;
    int q = (e >= -6) ? (e - 3) : -9;
    float scale = __uint_as_float((unsigned int)(127 - q) << 23);
    int m = __float2int_rn(a * scale);
    if (e >= -6) {
        if (m == 16) { m = 8; e += 1; }
        return (unsigned char)(s | ((unsigned int)(e + 7) << 3) | (unsigned int)(m - 8));
    } else {
        if (m == 8) return (unsigned char)(s | (1u << 3));
        return (unsigned char)(s | (unsigned int)m);
    }
}
__device__ __forceinline__ float e42f(unsigned char b) {
    unsigned int s = ((unsigned int)(b & 0x80u)) << 24;
    unsigned int ef = (b >> 3) & 0xFu, mf = b & 7u;
    float mag = (ef == 0) ? ((float)mf) * 0x1p-9f
                          : __uint_as_float(((ef + 120u) << 23) | (mf << 20));
    return __uint_as_float(__float_as_uint(mag) | s);
}

// ===========================================================================
// One-shot prep: all 12 weight matrices -> transposed split bf16 hi/lo
// [WTR rows][KP], zero-padded; also zeroes the BN stat accumulators.
// ===========================================================================
__global__ void prep_all(const float* __restrict__ nW2, const float* __restrict__ eW2,
                         const float* __restrict__ mW1, const float* __restrict__ mW2,
                         unsigned short* __restrict__ wt,
                         double* __restrict__ bnsum, double* __restrict__ bnsq)
{
    const int per = WTR * KP;
    int id = blockIdx.x * 256 + threadIdx.x;
    if (id < 12 * per) {
        int m = id / per, r = id - m * per;
        int col = r / KP, k = r - col * KP;
        const float* W = (m == 0) ? nW2 : (m == 1) ? eW2
                       : (m < 7) ? (mW1 + (size_t)(m - 2) * DD * DD)
                                 : (mW2 + (size_t)(m - 7) * DD * DD);
        float v = (col < DD && k < DD) ? W[(size_t)k * DD + col] : 0.f;
        unsigned short h = f2bf(v);
        wt[(size_t)m * 2 * per + (size_t)col * KP + k] = h;
        wt[(size_t)m * 2 * per + per + (size_t)col * KP + k] = f2bf(v - bf2f(h));
    } else if (id < 12 * per + DD) {
        int c = id - 12 * per;
        bnsum[c] = 0.0; bnsq[c] = 0.0;
    }
}

// ===========================================================================
// MFMA split-bf16 GEMM:  C[M,300] = f(A[M,300] @ B[300,300] + bias)
// B pre-transposed/pre-split, staged via global_load_lds (async DMA).
// Split product: Ah*Bh + Ah*Bl + Al*Bh  (error ~1e-5, fp32-equivalent here)
// ===========================================================================
enum { MA_SUM2 = 0, MA_BF16 = 1, MA_NODE = 2, MA_EDGE = 3 };
enum { ME_RELU = 0, ME_BN = 1, ME_EMB = 2, ME_FP8 = 3 };

constexpr int TM = 128;
constexpr int TN = 128;
constexpr int TK = 32;
constexpr int KSTEPS = 10;   // 320 = KP
constexpr int BP = 32;       // B tile pitch (contiguous: gload_lds dest)

template<int AM, int EM>
__launch_bounds__(256)
__global__ void mgemm(const unsigned short* __restrict__ Aa,
                      const unsigned short* __restrict__ Ab,
                      const unsigned short* __restrict__ Bth,
                      const unsigned short* __restrict__ Btl,
                      const float* __restrict__ bias,
                      const float* __restrict__ W1,
                      const float* __restrict__ b1,
                      const int* __restrict__ zidx,
                      const float* __restrict__ emb,
                      const int* __restrict__ permpos,
                      void* __restrict__ Cv,
                      double* __restrict__ bnsum, double* __restrict__ bnsq,
                      int M)
{
    constexpr bool SPLITA = (AM != MA_BF16);
    constexpr int AP = (AM == MA_BF16) ? 32 : 40;   // bf16 A staged by DMA (pitch 32)
    __shared__ unsigned short sAh[TM * AP];
    __shared__ unsigned short sBh[TN * BP];
    __shared__ unsigned short sBl[TN * BP];
    __shared__ unsigned short sAl[SPLITA ? TM * 40 : 64];

    const int t    = threadIdx.x;
    const int col0 = blockIdx.x * TN;
    const int row0 = blockIdx.y * TM;
    const int lane = t & 63;
    const int wid  = t >> 6;
    const int wr   = wid >> 1;            // wave row (64 rows)
    const int wc   = wid & 1;             // wave col (64 cols)
    const int lr   = lane & 15;
    const int lk   = lane >> 4;           // 0..3

    // manual staging assignment
    const int arow = t >> 1;              // 0..127
    const int akq  = (t & 1) * 16;        // 0 / 16 (k offset)
    // DMA staging assignment (16 rows x 64 B per instruction)
    const int dmarow = lane >> 2;         // 0..15
    const int dmakq  = (lane & 3) * 8;    // shorts: 0,8,16,24
    const int wbase  = wid * 32;          // rows handled by this wave

    const int ga = row0 + arow;
    float f0 = 0.f, f1 = 0.f, f2 = 0.f;
    if (AM == MA_NODE && ga < M) {
        f0 = ((const float*)Aa)[ga]; f1 = ((const float*)Ab)[ga];
    }
    if (AM == MA_EDGE && ga < M) {
        const float* Af = (const float*)Aa;
        f0 = Af[(size_t)ga * 3 + 0];
        f1 = Af[(size_t)ga * 3 + 1];
        f2 = Af[(size_t)ga * 3 + 2];
    }

    f32x4 acc[4][4];
#pragma unroll
    for (int i = 0; i < 4; ++i)
#pragma unroll
        for (int j = 0; j < 4; ++j) acc[i][j] = (f32x4){0.f, 0.f, 0.f, 0.f};

    for (int ks = 0; ks < KSTEPS; ++ks) {
        const int k0 = ks * TK;
        __syncthreads();

        // ---- stage B via async DMA: rows wbase..wbase+31, 2 instr/tile/wave
#pragma unroll
        for (int i = 0; i < 2; ++i) {
            const int rb = wbase + i * 16;
            gload16(Bth + (size_t)(col0 + rb + dmarow) * KP + k0 + dmakq, &sBh[rb * BP]);
            gload16(Btl + (size_t)(col0 + rb + dmarow) * KP + k0 + dmakq, &sBl[rb * BP]);
        }

        // ---- stage A ----
        if (AM == MA_BF16) {
            // pure bf16 copy: DMA (A buffer row-padded; k-spill hits zero B cols)
#pragma unroll
            for (int i = 0; i < 2; ++i) {
                const int rb = wbase + i * 16;
                gload16(Aa + (size_t)(row0 + rb + dmarow) * DD + k0 + dmakq, &sAh[rb * AP]);
            }
        } else {
            float v[16];
#pragma unroll
            for (int q = 0; q < 4; ++q) {
                const int k = k0 + akq + q * 4;
                if (AM == MA_SUM2) {
                    if (ga < M && k < DD) {
                        ushort4 ua = *(const ushort4*)(Aa + (size_t)ga * DD + k);
                        ushort4 ub = *(const ushort4*)(Ab + (size_t)ga * DD + k);
                        v[q*4+0] = bf2f(ua.x) + bf2f(ub.x);
                        v[q*4+1] = bf2f(ua.y) + bf2f(ub.y);
                        v[q*4+2] = bf2f(ua.z) + bf2f(ub.z);
                        v[q*4+3] = bf2f(ua.w) + bf2f(ub.w);
                    } else {
                        v[q*4+0] = v[q*4+1] = v[q*4+2] = v[q*4+3] = 0.f;
                    }
                } else {  // NODE / EDGE: relu(feats @ W1 + b1) on the fly
                    if (ga < M && k < DD) {
                        float4 w0 = ld4(W1 + k);
                        float4 w1 = ld4(W1 + DD + k);
                        float4 bb = ld4(b1 + k);
                        if (AM == MA_NODE) {
                            v[q*4+0] = fmaxf(fmaf(f0, w0.x, fmaf(f1, w1.x, bb.x)), 0.f);
                            v[q*4+1] = fmaxf(fmaf(f0, w0.y, fmaf(f1, w1.y, bb.y)), 0.f);
                            v[q*4+2] = fmaxf(fmaf(f0, w0.z, fmaf(f1, w1.z, bb.z)), 0.f);
                            v[q*4+3] = fmaxf(fmaf(f0, w0.w, fmaf(f1, w1.w, bb.w)), 0.f);
                        } else {
                            float4 w2 = ld4(W1 + 2 * DD + k);
                            v[q*4+0] = fmaxf(f0*w0.x + f1*w1.x + f2*w2.x + bb.x, 0.f);
                            v[q*4+1] = fmaxf(f0*w0.y + f1*w1.y + f2*w2.y + bb.y, 0.f);
                            v[q*4+2] = fmaxf(f0*w0.z + f1*w1.z + f2*w2.z + bb.z, 0.f);
                            v[q*4+3] = fmaxf(f0*w0.w + f1*w1.w + f2*w2.w + bb.w, 0.f);
                        }
                    } else {
                        v[q*4+0] = v[q*4+1] = v[q*4+2] = v[q*4+3] = 0.f;
                    }
                }
            }
#pragma unroll
            for (int q = 0; q < 4; ++q) {
                ushort4 hi, lo;
                hi.x = f2bf(v[q*4+0]); lo.x = f2bf(v[q*4+0] - bf2f(hi.x));
                hi.y = f2bf(v[q*4+1]); lo.y = f2bf(v[q*4+1] - bf2f(hi.y));
                hi.z = f2bf(v[q*4+2]); lo.z = f2bf(v[q*4+2] - bf2f(hi.z));
                hi.w = f2bf(v[q*4+3]); lo.w = f2bf(v[q*4+3] - bf2f(hi.w));
                *(ushort4*)&sAh[arow * AP + akq + q * 4] = hi;
                *(ushort4*)&sAl[arow * 40 + akq + q * 4] = lo;
            }
        }
        __syncthreads();   // compiler drains vmcnt (DMA) + lgkm before barrier

        // ---- fragments + MFMA ----
        short8v aH[4], aL[4], bH[4], bL[4];
#pragma unroll
        for (int f = 0; f < 4; ++f) {
            aH[f] = *(const short8v*)&sAh[(wr * 64 + f * 16 + lr) * AP + lk * 8];
            bH[f] = *(const short8v*)&sBh[(wc * 64 + f * 16 + lr) * BP + lk * 8];
            bL[f] = *(const short8v*)&sBl[(wc * 64 + f * 16 + lr) * BP + lk * 8];
            if constexpr (SPLITA)
                aL[f] = *(const short8v*)&sAl[(wr * 64 + f * 16 + lr) * 40 + lk * 8];
        }
#pragma unroll
        for (int fi = 0; fi < 4; ++fi)
#pragma unroll
            for (int fj = 0; fj < 4; ++fj) {
                acc[fi][fj] = __builtin_amdgcn_mfma_f32_16x16x32_bf16(aH[fi], bH[fj], acc[fi][fj], 0, 0, 0);
                acc[fi][fj] = __builtin_amdgcn_mfma_f32_16x16x32_bf16(aH[fi], bL[fj], acc[fi][fj], 0, 0, 0);
                if constexpr (SPLITA)
                    acc[fi][fj] = __builtin_amdgcn_mfma_f32_16x16x32_bf16(aL[fi], bH[fj], acc[fi][fj], 0, 0, 0);
            }
    }

    // ---- epilogue: C row = row0+wr*64+fi*16+lk*4+i, col = col0+wc*64+fj*16+lr
    float csum[4], csq[4];
#pragma unroll
    for (int j = 0; j < 4; ++j) { csum[j] = 0.f; csq[j] = 0.f; }

#pragma unroll
    for (int fi = 0; fi < 4; ++fi) {
#pragma unroll
        for (int i = 0; i < 4; ++i) {
            const int r = row0 + wr * 64 + fi * 16 + lk * 4 + i;
            if (r < M) {
                int zr = 0, pr = 0;
                if (EM == ME_EMB) zr = zidx[r];
                if (EM == ME_FP8) pr = permpos[r];
#pragma unroll
                for (int fj = 0; fj < 4; ++fj) {
                    const int c = col0 + wc * 64 + fj * 16 + lr;
                    if (c < DD) {
                        float v = acc[fi][fj][i] + bias[c];
                        if (EM == ME_RELU) v = fmaxf(v, 0.f);
                        if (EM == ME_EMB)  v += emb[(size_t)zr * DD + c];
                        if (EM == ME_FP8)
                            ((unsigned char*)Cv)[(size_t)pr * DD + c] = f2e4(v);
                        else
                            ((unsigned short*)Cv)[(size_t)r * DD + c] = f2bf(v);
                        if (EM == ME_BN) { csum[fj] += v; csq[fj] += v * v; }
                    }
                }
            }
        }
    }

    if (EM == ME_BN) {
        // Per-column stats: shuffle-reduce lanes {l,l^16,l^32,l^48}, then
        // combine wave-rows via sRed[2][TN] (row=wr, col=wc*64+fj*16+lr).
#pragma unroll
        for (int fj = 0; fj < 4; ++fj) {
            csum[fj] += __shfl_xor(csum[fj], 16);
            csum[fj] += __shfl_xor(csum[fj], 32);
            csq[fj]  += __shfl_xor(csq[fj], 16);
            csq[fj]  += __shfl_xor(csq[fj], 32);
        }
        float* sRed = (float*)sAh;   // 2*128 floats, tiles are dead
        __syncthreads();
        if (lk == 0) {
#pragma unroll
            for (int fj = 0; fj < 4; ++fj)
                sRed[wr * TN + wc * 64 + fj * 16 + lr] = csum[fj];
        }
        __syncthreads();
        if (t < TN) {
            float s = sRed[t] + sRed[TN + t];
            const int c = col0 + t;
            if (c < DD) unsafeAtomicAdd(&bnsum[c], (double)s);
        }
        __syncthreads();
        if (lk == 0) {
#pragma unroll
            for (int fj = 0; fj < 4; ++fj)
                sRed[wr * TN + wc * 64 + fj * 16 + lr] = csq[fj];
        }
        __syncthreads();
        if (t < TN) {
            float s = sRed[t] + sRed[TN + t];
            const int c = col0 + t;
            if (c < DD) unsafeAtomicAdd(&bnsq[c], (double)s);
        }
    }
}

// ===========================================================================
// fp32 VALU GEMM kept only for the tiny final projection (G=4096)
// ===========================================================================
constexpr int GBM = 128;
constexpr int GBN = 128;
constexpr int GBK = 8;
constexpr int KPAD = 304;

__launch_bounds__(256)
__global__ void gemm_final(const float* __restrict__ Aa, const float* __restrict__ Bw,
                           const float* __restrict__ bias, float* __restrict__ C, int M)
{
    __shared__ float smem[2 * GBK * GBM];
    float* As = smem;
    float* Bs = smem + GBK * GBM;

    const int t    = threadIdx.x;
    const int tx   = t & 15;
    const int ty   = t >> 4;
    const int col0 = blockIdx.x * GBN;
    const int row0 = blockIdx.y * GBM;
    const int arow = t >> 1;
    const int akq  = (t & 1) << 2;
    const int brow = t >> 5;
    const int bnq  = (t & 31) << 2;
    const int ga   = row0 + arow;
    const int gb   = col0 + bnq;

    float acc[8][8];
#pragma unroll
    for (int i = 0; i < 8; ++i)
#pragma unroll
        for (int j = 0; j < 8; ++j) acc[i][j] = 0.f;

    for (int k0 = 0; k0 < KPAD; k0 += GBK) {
        float4 av = make_float4(0.f, 0.f, 0.f, 0.f);
        const int ka = k0 + akq;
        if (ga < M && ka < DD) av = ld4(Aa + (size_t)ga * DD + ka);
        As[(akq + 0) * GBM + arow] = av.x;
        As[(akq + 1) * GBM + arow] = av.y;
        As[(akq + 2) * GBM + arow] = av.z;
        As[(akq + 3) * GBM + arow] = av.w;

        float4 bv = make_float4(0.f, 0.f, 0.f, 0.f);
        const int kb = k0 + brow;
        if (kb < DD && gb < DD) bv = ld4(Bw + (size_t)kb * DD + gb);
        *(float4*)(Bs + brow * GBN + bnq) = bv;

        __syncthreads();
#pragma unroll
        for (int kk = 0; kk < GBK; ++kk) {
            float a[8], b[8];
            *(float4*)&a[0] = *(const float4*)(As + kk * GBM + 8 * ty);
            *(float4*)&a[4] = *(const float4*)(As + kk * GBM + 8 * ty + 4);
            *(float4*)&b[0] = *(const float4*)(Bs + kk * GBN + 8 * tx);
            *(float4*)&b[4] = *(const float4*)(Bs + kk * GBN + 8 * tx + 4);
#pragma unroll
            for (int i = 0; i < 8; ++i)
#pragma unroll
                for (int j = 0; j < 8; ++j)
                    acc[i][j] = fmaf(a[i], b[j], acc[i][j]);
        }
        __syncthreads();
    }

#pragma unroll
    for (int i = 0; i < 8; ++i) {
        const int r = row0 + 8 * ty + i;
        if (r < M) {
#pragma unroll
            for (int jq = 0; jq < 2; ++jq) {
                const int c = col0 + 8 * tx + 4 * jq;
                if (c < DD) {
                    float4 bb = ld4(bias + c);
                    *(float4*)(C + (size_t)r * DD + c) = make_float4(
                        acc[i][4*jq+0] + bb.x, acc[i][4*jq+1] + bb.y,
                        acc[i][4*jq+2] + bb.z, acc[i][4*jq+3] + bb.w);
                }
            }
        }
    }
}

// ===========================================================================
// CSR build
// ===========================================================================
__global__ void deg_kernel(const int* __restrict__ dst, int* __restrict__ deg, int E)
{
    int e = blockIdx.x * 256 + threadIdx.x;
    if (e < E) atomicAdd(&deg[dst[e]], 1);
}

__global__ void scan1(const int* __restrict__ deg, int* __restrict__ out,
                      int* __restrict__ bsum, int n)
{
    __shared__ int sh[256];
    const int t = threadIdx.x;
    const int base = blockIdx.x * 1024 + t * 4;
    int v0 = (base + 0 < n) ? deg[base + 0] : 0;
    int v1 = (base + 1 < n) ? deg[base + 1] : 0;
    int v2 = (base + 2 < n) ? deg[base + 2] : 0;
    int v3 = (base + 3 < n) ? deg[base + 3] : 0;
    const int s = v0 + v1 + v2 + v3;
    sh[t] = s;
    __syncthreads();
    for (int off = 1; off < 256; off <<= 1) {
        int x = (t >= off) ? sh[t - off] : 0;
        __syncthreads();
        sh[t] += x;
        __syncthreads();
    }
    int ex = sh[t] - s;
    if (base + 0 < n) out[base + 0] = ex; ex += v0;
    if (base + 1 < n) out[base + 1] = ex; ex += v1;
    if (base + 2 < n) out[base + 2] = ex; ex += v2;
    if (base + 3 < n) out[base + 3] = ex;
    if (t == 255) bsum[blockIdx.x] = sh[255];
}

__global__ void scan2(int* __restrict__ bsum, int nb, int* __restrict__ offs, int n, int E)
{
    __shared__ int sh[256];
    const int t = threadIdx.x;
    const int v = (t < nb) ? bsum[t] : 0;
    sh[t] = v;
    __syncthreads();
    for (int off = 1; off < 256; off <<= 1) {
        int x = (t >= off) ? sh[t - off] : 0;
        __syncthreads();
        sh[t] += x;
        __syncthreads();
    }
    if (t < nb) bsum[t] = sh[t] - v;
    if (t == 0) offs[n] = E;
}

__global__ void scan3(int* __restrict__ offs, const int* __restrict__ bsum,
                      int* __restrict__ cursor, int n)
{
    int i = blockIdx.x * 256 + threadIdx.x;
    if (i < n) {
        int v = offs[i] + bsum[i >> 10];
        offs[i] = v;
        cursor[i] = v;
    }
}

__global__ void fill_kernel(const int* __restrict__ src, const int* __restrict__ dst,
                            int* __restrict__ cursor, int* __restrict__ esrc,
                            int* __restrict__ permpos, int E)
{
    int e = blockIdx.x * 256 + threadIdx.x;
    if (e < E) {
        int d = dst[e];
        int pos = atomicAdd(&cursor[d], 1);
        esrc[pos] = src[e];
        permpos[e] = pos;
    }
}

// ===========================================================================
// agg[i] = sum_in relu(h[src] + e[slot]);  4 nodes/block (1 wave each)
// ===========================================================================
__global__ void agg_kernel(const unsigned short* __restrict__ h,
                           const unsigned char* __restrict__ e,
                           const int* __restrict__ esrc, const int* __restrict__ offs,
                           unsigned short* __restrict__ agg, int N)
{
    const int node = blockIdx.x * 4 + (threadIdx.x >> 6);
    if (node >= N) return;
    const int lane = threadIdx.x & 63;
    const int beg = offs[node], end = offs[node + 1];
    for (int q = lane; q < 75; q += 64) {
        float4 s = make_float4(0.f, 0.f, 0.f, 0.f);
        for (int p = beg; p < end; ++p) {
            const int src = esrc[p];
            ushort4 hu = *(const ushort4*)(h + (size_t)src * DD + 4 * q);
            unsigned int eu = *(const unsigned int*)(e + (size_t)p * DD + 4 * q);
            s.x += fmaxf(bf2f(hu.x) + e42f((unsigned char)(eu & 0xFF)), 0.f);
            s.y += fmaxf(bf2f(hu.y) + e42f((unsigned char)((eu >> 8) & 0xFF)), 0.f);
            s.z += fmaxf(bf2f(hu.z) + e42f((unsigned char)((eu >> 16) & 0xFF)), 0.f);
            s.w += fmaxf(bf2f(hu.w) + e42f((unsigned char)(eu >> 24)), 0.f);
        }
        *(ushort4*)(agg + (size_t)node * DD + 4 * q) =
            make_ushort4(f2bf(s.x), f2bf(s.y), f2bf(s.z), f2bf(s.w));
    }
}

// ===========================================================================
// BatchNorm finalize (re-zeroes accumulators for the next layer) + apply
// ===========================================================================
__global__ void bn_fin(double* __restrict__ bnsum, double* __restrict__ bnsq,
                       const float* __restrict__ gamma, const float* __restrict__ beta,
                       float* __restrict__ scale, float* __restrict__ shift, double invN)
{
    const int c = threadIdx.x;
    if (c < DD) {
        double mu = bnsum[c] * invN;
        double var = bnsq[c] * invN - mu * mu;
        double inv = 1.0 / sqrt(var + 1e-5);
        double g = (double)gamma[c];
        scale[c] = (float)(g * inv);
        shift[c] = (float)((double)beta[c] - mu * inv * g);
        bnsum[c] = 0.0;
        bnsq[c]  = 0.0;
    }
}

__global__ void bn_apply(const unsigned short* __restrict__ h2,
                         const float* __restrict__ scale, const float* __restrict__ shift,
                         unsigned short* __restrict__ h, int total4)
{
    int idx = blockIdx.x * 256 + threadIdx.x;
    if (idx >= total4) return;
    int q = idx % 75;
    ushort4 v4 = ((const ushort4*)h2)[idx];
    float4 sc = ld4(scale + 4 * q);
    float4 sh = ld4(shift + 4 * q);
    float r0 = fmaxf(fmaf(bf2f(v4.x), sc.x, sh.x), 0.f);
    float r1 = fmaxf(fmaf(bf2f(v4.y), sc.y, sh.y), 0.f);
    float r2 = fmaxf(fmaf(bf2f(v4.z), sc.z, sh.z), 0.f);
    float r3 = fmaxf(fmaf(bf2f(v4.w), sc.w, sh.w), 0.f);
    ((ushort4*)h)[idx] = make_ushort4(f2bf(r0), f2bf(r1), f2bf(r2), f2bf(r3));
}

// ===========================================================================
// Per-graph mean pooling
// ===========================================================================
__global__ void pool_kernel(const unsigned short* __restrict__ h, const int* __restrict__ batch,
                            float* __restrict__ pooled, int N)
{
    const int g = blockIdx.x;
    __shared__ int sb[2];
    if (threadIdx.x == 0) {
        int lo = 0, hi = N;
        while (lo < hi) { int m = (lo + hi) >> 1; if (batch[m] < g) lo = m + 1; else hi = m; }
        sb[0] = lo;
        lo = 0; hi = N;
        while (lo < hi) { int m = (lo + hi) >> 1; if (batch[m] < g + 1) lo = m + 1; else hi = m; }
        sb[1] = lo;
    }
    __syncthreads();
    const int beg = sb[0], end = sb[1];
    const float cnt = (float)(end - beg);
    for (int d = threadIdx.x; d < DD; d += 256) {
        float s = 0.f;
        for (int i = beg; i < end; ++i) s += bf2f(h[(size_t)i * DD + d]);
        pooled[(size_t)g * DD + d] = (end > beg) ? (s / cnt) : 0.f;
    }
}

__global__ void diag_fill(float* __restrict__ out, int n, float v)
{
    int i = blockIdx.x * 256 + threadIdx.x;
    if (i < n) out[i] = v;
}

// ===========================================================================
extern "C" void kernel_launch(void* const* d_in, const int* in_sizes, int n_in,
                              void* d_out, int out_size, void* d_ws, size_t ws_size,
                              hipStream_t stream)
{
    const int N = in_sizes[0];
    const int E = in_sizes[3] / 2;
    const int G = out_size / DD;
    const int NPAD = (N + 127) & ~127;

    const int*   z     = (const int*)d_in[0];
    const float* chir  = (const float*)d_in[1];
    const float* fc    = (const float*)d_in[2];
    const int*   eidx  = (const int*)d_in[3];
    const float* eattr = (const float*)d_in[4];
    const int*   batch = (const int*)d_in[5];
    const float* aemb  = (const float*)d_in[7];
    const float* nW1   = (const float*)d_in[8];
    const float* nb1   = (const float*)d_in[9];
    const float* nW2   = (const float*)d_in[10];
    const float* nb2   = (const float*)d_in[11];
    const float* eW1   = (const float*)d_in[12];
    const float* eb1   = (const float*)d_in[13];
    const float* eW2   = (const float*)d_in[14];
    const float* eb2   = (const float*)d_in[15];
    const float* mW1   = (const float*)d_in[16];
    const float* mb1   = (const float*)d_in[17];
    const float* mW2   = (const float*)d_in[18];
    const float* mb2   = (const float*)d_in[19];
    const float* gamma = (const float*)d_in[20];
    const float* beta  = (const float*)d_in[21];
    const float* pW    = (const float*)d_in[22];
    const float* pb    = (const float*)d_in[23];
    float* out = (float*)d_out;

    size_t base = 0;
    auto A = [&](size_t b) -> size_t {
        size_t r = base; base += (b + 255) & ~(size_t)255; return r;
    };
    const size_t o_h    = A((size_t)N * DD * 2);          // h bf16
    const size_t o_t    = A((size_t)NPAD * DD * 2 + 128); // tbuf bf16, row-padded (DMA A)
    const size_t o_g    = A((size_t)N * DD * 2);          // agg / h2 bf16
    const size_t o_bns  = A(DD * 8);
    const size_t o_bnq  = A(DD * 8);
    const size_t o_scl  = A(DD * 4);
    const size_t o_shf  = A(DD * 4);
    const size_t o_offs = A((size_t)(N + 1) * 4);
    const size_t o_cur  = A((size_t)N * 4);
    const size_t o_bsum = A(1024 * 4);
    const size_t o_src  = A((size_t)E * 4);
    const size_t o_perm = A((size_t)E * 4);
    const size_t o_wt   = A((size_t)12 * 2 * WTR * KP * 2);  // 12 matrices, hi+lo
    const size_t o_e    = A((size_t)E * DD * 1);          // ebuf fp8, CSR-permuted
    const size_t need = base;

    if (ws_size < need) {
        diag_fill<<<(out_size + 255) / 256, 256, 0, stream>>>(
            out, out_size, 10000.f + (float)(ws_size >> 20));
        return;
    }

    char* w = (char*)d_ws;
    unsigned short* h      = (unsigned short*)(w + o_h);
    unsigned short* tbuf   = (unsigned short*)(w + o_t);
    unsigned short* aggh2  = (unsigned short*)(w + o_g);
    double*         bnsum  = (double*)(w + o_bns);
    double*         bnsq   = (double*)(w + o_bnq);
    float*          scl    = (float*)(w + o_scl);
    float*          shf    = (float*)(w + o_shf);
    int*            offs   = (int*)(w + o_offs);
    int*            cursor = (int*)(w + o_cur);
    int*            bsum   = (int*)(w + o_bsum);
    int*            esrc   = (int*)(w + o_src);
    int*            permpos= (int*)(w + o_perm);
    unsigned short* wt     = (unsigned short*)(w + o_wt);
    unsigned char*  ebuf   = (unsigned char*)(w + o_e);
    float*          pooled = (float*)tbuf;

    // weight slots: m=0 nW2, m=1 eW2, m=2+l mW1[l], m=7+l mW2[l]
    const size_t per = (size_t)WTR * KP;
    auto wHI = [&](int m) { return wt + (size_t)m * 2 * per; };
    auto wLO = [&](int m) { return wt + (size_t)m * 2 * per + per; };

    const int* srcI = eidx;
    const int* dstI = eidx + E;

    // ---- one-shot prep: weights + BN accumulator zero ----
    const int ptot = 12 * WTR * KP + DD;
    prep_all<<<(ptot + 255) / 256, 256, 0, stream>>>(nW2, eW2, mW1, mW2, wt, bnsum, bnsq);

    // ---- CSR of incoming edges ----
    hipMemsetAsync(cursor, 0, (size_t)N * 4, stream);
    deg_kernel<<<(E + 255) / 256, 256, 0, stream>>>(dstI, cursor, E);
    const int nb = (N + 1023) / 1024;
    scan1<<<nb, 256, 0, stream>>>(cursor, offs, bsum, N);
    scan2<<<1, 256, 0, stream>>>(bsum, nb, offs, N, E);
    scan3<<<(N + 255) / 256, 256, 0, stream>>>(offs, bsum, cursor, N);
    fill_kernel<<<(E + 255) / 256, 256, 0, stream>>>(srcI, dstI, cursor, esrc, permpos, E);

    const dim3 gN(3, (N + TM - 1) / TM);
    const dim3 gE(3, (E + TM - 1) / TM);
    const dim3 gG(3, (G + GBM - 1) / GBM);

    // ---- encoders (MFMA) ----
    mgemm<MA_NODE, ME_EMB><<<gN, 256, 0, stream>>>(
        (const unsigned short*)chir, (const unsigned short*)fc, wHI(0), wLO(0), nb2,
        nW1, nb1, z, aemb, nullptr, h, nullptr, nullptr, N);
    mgemm<MA_EDGE, ME_FP8><<<gE, 256, 0, stream>>>(
        (const unsigned short*)eattr, nullptr, wHI(1), wLO(1), eb2,
        eW1, eb1, nullptr, nullptr, permpos, ebuf, nullptr, nullptr, E);

    // ---- 5 GINE layers ----
    for (int l = 0; l < 5; ++l) {
        agg_kernel<<<(N + 3) / 4, 256, 0, stream>>>(h, ebuf, esrc, offs, aggh2, N);
        mgemm<MA_SUM2, ME_RELU><<<gN, 256, 0, stream>>>(
            h, aggh2, wHI(2 + l), wLO(2 + l), mb1 + l * DD,
            nullptr, nullptr, nullptr, nullptr, nullptr, tbuf, nullptr, nullptr, N);
        mgemm<MA_BF16, ME_BN><<<gN, 256, 0, stream>>>(
            tbuf, nullptr, wHI(7 + l), wLO(7 + l), mb2 + l * DD,
            nullptr, nullptr, nullptr, nullptr, nullptr, aggh2, bnsum, bnsq, N);
        bn_fin<<<1, 320, 0, stream>>>(bnsum, bnsq, gamma + l * DD, beta + l * DD,
                                      scl, shf, 1.0 / (double)N);
        const int tot4 = N * 75;
        bn_apply<<<(tot4 + 255) / 256, 256, 0, stream>>>(aggh2, scl, shf, h, tot4);
    }

    // ---- pooling + final projection ----
    pool_kernel<<<G, 256, 0, stream>>>(h, batch, pooled, N);
    gemm_final<<<gG, 256, 0, stream>>>(pooled, pW, pb, out, G);
}

// Round 10
// 2726.520 us; speedup vs baseline: 1.3407x; 1.1843x over previous
//
#include <hip/hip_runtime.h>

#define DD 300
#define KP 320    // padded K for pre-transposed weights
#define WTR 384   // weight rows padded to 3*128 (no guard needed in DMA staging)

typedef __attribute__((ext_vector_type(8))) short short8v;   // 8 bf16 = 4 VGPR
typedef __attribute__((ext_vector_type(4))) float f32x4;

__device__ __forceinline__ float4 ld4(const float* p) { return *(const float4*)p; }

__device__ __forceinline__ unsigned short f2bf(float f) {
    unsigned int u = __float_as_uint(f);
    unsigned int r = (u + 0x7fffu + ((u >> 16) & 1u)) >> 16;   // RNE
    return (unsigned short)r;
}
__device__ __forceinline__ float bf2f(unsigned short b) {
    return __uint_as_float(((unsigned int)b) << 16);
}

// async global->LDS, 16 B per lane; LDS dest = base + lane*16
__device__ __forceinline__ void gload16(const void* g, void* l) {
    __builtin_amdgcn_global_load_lds(
        (const __attribute__((address_space(1))) unsigned int*)g,
        (__attribute__((address_space(3))) unsigned int*)l, 16, 0, 0);
}

// ---- manual OCP e4m3fn -----------------------------------------------------
__device__ __forceinline__ unsigned char f2e4(float f) {
    unsigned int u = __float_as_uint(f);
    unsigned int s = (u >> 24) & 0x80u;
    float a = __uint_as_float(u & 0x7fffffffu);
    if (a >= 448.f) return (unsigned char)(s | 0x7Eu);
    if (a < 0x1p-10f) return (unsigned char)s;
    int e = (int)((__float_as_uint(a) >> 23) & 0xFF) - 127;
    int q = (e >= -6) ? (e - 3) : -9;
    float scale = __uint_as_float((unsigned int)(127 - q) << 23);
    int m = __float2int_rn(a * scale);
    if (e >= -6) {
        if (m == 16) { m = 8; e += 1; }
        return (unsigned char)(s | ((unsigned int)(e + 7) << 3) | (unsigned int)(m - 8));
    } else {
        if (m == 8) return (unsigned char)(s | (1u << 3));
        return (unsigned char)(s | (unsigned int)m);
    }
}
__device__ __forceinline__ float e42f(unsigned char b) {
    unsigned int s = ((unsigned int)(b & 0x80u)) << 24;
    unsigned int ef = (b >> 3) & 0xFu, mf = b & 7u;
    float mag = (ef == 0) ? ((float)mf) * 0x1p-9f
                          : __uint_as_float(((ef + 120u) << 23) | (mf << 20));
    return __uint_as_float(__float_as_uint(mag) | s);
}

// ===========================================================================
// One-shot prep: all 12 weight matrices -> transposed split bf16 hi/lo
// [WTR rows][KP], zero-padded; also zeroes the BN stat accumulators.
// ===========================================================================
__global__ void prep_all(const float* __restrict__ nW2, const float* __restrict__ eW2,
                         const float* __restrict__ mW1, const float* __restrict__ mW2,
                         unsigned short* __restrict__ wt,
                         double* __restrict__ bnsum, double* __restrict__ bnsq)
{
    const int per = WTR * KP;
    int id = blockIdx.x * 256 + threadIdx.x;
    if (id < 12 * per) {
        int m = id / per, r = id - m * per;
        int col = r / KP, k = r - col * KP;
        const float* W = (m == 0) ? nW2 : (m == 1) ? eW2
                       : (m < 7) ? (mW1 + (size_t)(m - 2) * DD * DD)
                                 : (mW2 + (size_t)(m - 7) * DD * DD);
        float v = (col < DD && k < DD) ? W[(size_t)k * DD + col] : 0.f;
        unsigned short h = f2bf(v);
        wt[(size_t)m * 2 * per + (size_t)col * KP + k] = h;
        wt[(size_t)m * 2 * per + per + (size_t)col * KP + k] = f2bf(v - bf2f(h));
    } else if (id < 12 * per + DD) {
        int c = id - 12 * per;
        bnsum[c] = 0.0; bnsq[c] = 0.0;
    }
}

// ===========================================================================
// MFMA split-bf16 GEMM:  C[M,300] = f(A @ B + bias)
// Modes:
//   MA_DMA2: A = Aa + Ab, both exact-bf16 buffers, BOTH DMA-staged; 4 MFMA
//            per frag pair (= (Aa+Ab)@(Bh+Bl) exactly, fp32 accumulation)
//   MA_BF16: A exact bf16, DMA-staged; 2 MFMA
//   MA_NODE/MA_EDGE: A computed on the fly (feats@W1+b1, relu), split; 3 MFMA
// B always pre-transposed/pre-split, DMA-staged.
// ===========================================================================
enum { MA_DMA2 = 0, MA_BF16 = 1, MA_NODE = 2, MA_EDGE = 3 };
enum { ME_RELU = 0, ME_BN = 1, ME_EMB = 2, ME_FP8 = 3 };

constexpr int TM = 128;
constexpr int TN = 128;
constexpr int TK = 32;
constexpr int KSTEPS = 10;   // 320 = KP

template<int AM, int EM>
__launch_bounds__(256)
__global__ void mgemm(const unsigned short* __restrict__ Aa,
                      const unsigned short* __restrict__ Ab,
                      const unsigned short* __restrict__ Bth,
                      const unsigned short* __restrict__ Btl,
                      const float* __restrict__ bias,
                      const float* __restrict__ W1,
                      const float* __restrict__ b1,
                      const int* __restrict__ zidx,
                      const float* __restrict__ emb,
                      const int* __restrict__ permpos,
                      void* __restrict__ Cv,
                      double* __restrict__ bnsum, double* __restrict__ bnsq,
                      int M)
{
    constexpr bool VSTAGE = (AM == MA_NODE || AM == MA_EDGE);
    constexpr int AP = VSTAGE ? 40 : 32;
    __shared__ unsigned short sAh[TM * AP];
    __shared__ unsigned short sBh[TN * 32];
    __shared__ unsigned short sBl[TN * 32];
    __shared__ unsigned short sA2[(AM == MA_DMA2) ? TM * 32 : 64];  // agg tile (DMA)
    __shared__ unsigned short sAl[VSTAGE ? TM * 40 : 64];           // lo tile (VALU)

    const int t    = threadIdx.x;
    const int col0 = blockIdx.x * TN;
    const int row0 = blockIdx.y * TM;
    const int lane = t & 63;
    const int wid  = t >> 6;
    const int wr   = wid >> 1;            // wave row (64 rows)
    const int wc   = wid & 1;             // wave col (64 cols)
    const int lr   = lane & 15;
    const int lk   = lane >> 4;           // 0..3

    // VALU staging assignment
    const int arow = t >> 1;              // 0..127
    const int akq  = (t & 1) * 16;        // 0 / 16 (k offset)
    // DMA staging assignment (16 rows x 64 B per instruction)
    const int dmarow = lane >> 2;         // 0..15
    const int dmakq  = (lane & 3) * 8;    // shorts: 0,8,16,24
    const int wbase  = wid * 32;          // rows handled by this wave

    const int ga = row0 + arow;
    float f0 = 0.f, f1 = 0.f, f2 = 0.f;
    if (AM == MA_NODE && ga < M) {
        f0 = ((const float*)Aa)[ga]; f1 = ((const float*)Ab)[ga];
    }
    if (AM == MA_EDGE && ga < M) {
        const float* Af = (const float*)Aa;
        f0 = Af[(size_t)ga * 3 + 0];
        f1 = Af[(size_t)ga * 3 + 1];
        f2 = Af[(size_t)ga * 3 + 2];
    }

    f32x4 acc[4][4];
#pragma unroll
    for (int i = 0; i < 4; ++i)
#pragma unroll
        for (int j = 0; j < 4; ++j) acc[i][j] = (f32x4){0.f, 0.f, 0.f, 0.f};

    for (int ks = 0; ks < KSTEPS; ++ks) {
        const int k0 = ks * TK;
        __syncthreads();

        // ---- stage B via async DMA: rows wbase..wbase+31, 2 instr/tile/wave
#pragma unroll
        for (int i = 0; i < 2; ++i) {
            const int rb = wbase + i * 16;
            gload16(Bth + (size_t)(col0 + rb + dmarow) * KP + k0 + dmakq, &sBh[rb * 32]);
            gload16(Btl + (size_t)(col0 + rb + dmarow) * KP + k0 + dmakq, &sBl[rb * 32]);
        }

        // ---- stage A ----
        if (AM == MA_DMA2) {
            // both A operands are exact bf16 buffers: pure DMA
            // (pitch DD=300; k in [300,320) spills into next row -> multiplies
            //  zero-padded B rows, so garbage is harmless; buffers row-padded)
#pragma unroll
            for (int i = 0; i < 2; ++i) {
                const int rb = wbase + i * 16;
                gload16(Aa + (size_t)(row0 + rb + dmarow) * DD + k0 + dmakq, &sAh[rb * 32]);
                gload16(Ab + (size_t)(row0 + rb + dmarow) * DD + k0 + dmakq, &sA2[rb * 32]);
            }
        } else if (AM == MA_BF16) {
#pragma unroll
            for (int i = 0; i < 2; ++i) {
                const int rb = wbase + i * 16;
                gload16(Aa + (size_t)(row0 + rb + dmarow) * DD + k0 + dmakq, &sAh[rb * 32]);
            }
        } else {
            float v[16];
#pragma unroll
            for (int q = 0; q < 4; ++q) {
                const int k = k0 + akq + q * 4;
                if (ga < M && k < DD) {
                    float4 w0 = ld4(W1 + k);
                    float4 w1 = ld4(W1 + DD + k);
                    float4 bb = ld4(b1 + k);
                    if (AM == MA_NODE) {
                        v[q*4+0] = fmaxf(fmaf(f0, w0.x, fmaf(f1, w1.x, bb.x)), 0.f);
                        v[q*4+1] = fmaxf(fmaf(f0, w0.y, fmaf(f1, w1.y, bb.y)), 0.f);
                        v[q*4+2] = fmaxf(fmaf(f0, w0.z, fmaf(f1, w1.z, bb.z)), 0.f);
                        v[q*4+3] = fmaxf(fmaf(f0, w0.w, fmaf(f1, w1.w, bb.w)), 0.f);
                    } else {
                        float4 w2 = ld4(W1 + 2 * DD + k);
                        v[q*4+0] = fmaxf(f0*w0.x + f1*w1.x + f2*w2.x + bb.x, 0.f);
                        v[q*4+1] = fmaxf(f0*w0.y + f1*w1.y + f2*w2.y + bb.y, 0.f);
                        v[q*4+2] = fmaxf(f0*w0.z + f1*w1.z + f2*w2.z + bb.z, 0.f);
                        v[q*4+3] = fmaxf(f0*w0.w + f1*w1.w + f2*w2.w + bb.w, 0.f);
                    }
                } else {
                    v[q*4+0] = v[q*4+1] = v[q*4+2] = v[q*4+3] = 0.f;
                }
            }
#pragma unroll
            for (int q = 0; q < 4; ++q) {
                ushort4 hi, lo;
                hi.x = f2bf(v[q*4+0]); lo.x = f2bf(v[q*4+0] - bf2f(hi.x));
                hi.y = f2bf(v[q*4+1]); lo.y = f2bf(v[q*4+1] - bf2f(hi.y));
                hi.z = f2bf(v[q*4+2]); lo.z = f2bf(v[q*4+2] - bf2f(hi.z));
                hi.w = f2bf(v[q*4+3]); lo.w = f2bf(v[q*4+3] - bf2f(hi.w));
                *(ushort4*)&sAh[arow * AP + akq + q * 4] = hi;
                *(ushort4*)&sAl[arow * 40 + akq + q * 4] = lo;
            }
        }
        __syncthreads();   // compiler drains vmcnt (DMA) + lgkm before barrier

        // ---- fragments + MFMA ----
        short8v aH[4], aX[4], bH[4], bL[4];
#pragma unroll
        for (int f = 0; f < 4; ++f) {
            aH[f] = *(const short8v*)&sAh[(wr * 64 + f * 16 + lr) * AP + lk * 8];
            bH[f] = *(const short8v*)&sBh[(wc * 64 + f * 16 + lr) * 32 + lk * 8];
            bL[f] = *(const short8v*)&sBl[(wc * 64 + f * 16 + lr) * 32 + lk * 8];
            if constexpr (AM == MA_DMA2)
                aX[f] = *(const short8v*)&sA2[(wr * 64 + f * 16 + lr) * 32 + lk * 8];
            if constexpr (VSTAGE)
                aX[f] = *(const short8v*)&sAl[(wr * 64 + f * 16 + lr) * 40 + lk * 8];
        }
#pragma unroll
        for (int fi = 0; fi < 4; ++fi)
#pragma unroll
            for (int fj = 0; fj < 4; ++fj) {
                acc[fi][fj] = __builtin_amdgcn_mfma_f32_16x16x32_bf16(aH[fi], bH[fj], acc[fi][fj], 0, 0, 0);
                acc[fi][fj] = __builtin_amdgcn_mfma_f32_16x16x32_bf16(aH[fi], bL[fj], acc[fi][fj], 0, 0, 0);
                if constexpr (AM == MA_DMA2) {
                    acc[fi][fj] = __builtin_amdgcn_mfma_f32_16x16x32_bf16(aX[fi], bH[fj], acc[fi][fj], 0, 0, 0);
                    acc[fi][fj] = __builtin_amdgcn_mfma_f32_16x16x32_bf16(aX[fi], bL[fj], acc[fi][fj], 0, 0, 0);
                }
                if constexpr (VSTAGE)
                    acc[fi][fj] = __builtin_amdgcn_mfma_f32_16x16x32_bf16(aX[fi], bH[fj], acc[fi][fj], 0, 0, 0);
            }
    }

    // ---- epilogue: C row = row0+wr*64+fi*16+lk*4+i, col = col0+wc*64+fj*16+lr
    float csum[4], csq[4];
#pragma unroll
    for (int j = 0; j < 4; ++j) { csum[j] = 0.f; csq[j] = 0.f; }

#pragma unroll
    for (int fi = 0; fi < 4; ++fi) {
#pragma unroll
        for (int i = 0; i < 4; ++i) {
            const int r = row0 + wr * 64 + fi * 16 + lk * 4 + i;
            if (r < M) {
                int zr = 0, pr = 0;
                if (EM == ME_EMB) zr = zidx[r];
                if (EM == ME_FP8) pr = permpos[r];
#pragma unroll
                for (int fj = 0; fj < 4; ++fj) {
                    const int c = col0 + wc * 64 + fj * 16 + lr;
                    if (c < DD) {
                        float v = acc[fi][fj][i] + bias[c];
                        if (EM == ME_RELU) v = fmaxf(v, 0.f);
                        if (EM == ME_EMB)  v += emb[(size_t)zr * DD + c];
                        if (EM == ME_FP8)
                            ((unsigned char*)Cv)[(size_t)pr * DD + c] = f2e4(v);
                        else
                            ((unsigned short*)Cv)[(size_t)r * DD + c] = f2bf(v);
                        if (EM == ME_BN) { csum[fj] += v; csq[fj] += v * v; }
                    }
                }
            }
        }
    }

    if (EM == ME_BN) {
        // Per-column stats: shuffle-reduce lanes {l,l^16,l^32,l^48}, then
        // combine wave-rows via sRed[2][TN] (row=wr, col=wc*64+fj*16+lr).
#pragma unroll
        for (int fj = 0; fj < 4; ++fj) {
            csum[fj] += __shfl_xor(csum[fj], 16);
            csum[fj] += __shfl_xor(csum[fj], 32);
            csq[fj]  += __shfl_xor(csq[fj], 16);
            csq[fj]  += __shfl_xor(csq[fj], 32);
        }
        float* sRed = (float*)sAh;   // 2*128 floats, tiles are dead
        __syncthreads();
        if (lk == 0) {
#pragma unroll
            for (int fj = 0; fj < 4; ++fj)
                sRed[wr * TN + wc * 64 + fj * 16 + lr] = csum[fj];
        }
        __syncthreads();
        if (t < TN) {
            float s = sRed[t] + sRed[TN + t];
            const int c = col0 + t;
            if (c < DD) unsafeAtomicAdd(&bnsum[c], (double)s);
        }
        __syncthreads();
        if (lk == 0) {
#pragma unroll
            for (int fj = 0; fj < 4; ++fj)
                sRed[wr * TN + wc * 64 + fj * 16 + lr] = csq[fj];
        }
        __syncthreads();
        if (t < TN) {
            float s = sRed[t] + sRed[TN + t];
            const int c = col0 + t;
            if (c < DD) unsafeAtomicAdd(&bnsq[c], (double)s);
        }
    }
}

// ===========================================================================
// fp32 VALU GEMM kept only for the tiny final projection (G=4096)
// ===========================================================================
constexpr int GBM = 128;
constexpr int GBN = 128;
constexpr int GBK = 8;
constexpr int KPAD = 304;

__launch_bounds__(256)
__global__ void gemm_final(const float* __restrict__ Aa, const float* __restrict__ Bw,
                           const float* __restrict__ bias, float* __restrict__ C, int M)
{
    __shared__ float smem[2 * GBK * GBM];
    float* As = smem;
    float* Bs = smem + GBK * GBM;

    const int t    = threadIdx.x;
    const int tx   = t & 15;
    const int ty   = t >> 4;
    const int col0 = blockIdx.x * GBN;
    const int row0 = blockIdx.y * GBM;
    const int arow = t >> 1;
    const int akq  = (t & 1) << 2;
    const int brow = t >> 5;
    const int bnq  = (t & 31) << 2;
    const int ga   = row0 + arow;
    const int gb   = col0 + bnq;

    float acc[8][8];
#pragma unroll
    for (int i = 0; i < 8; ++i)
#pragma unroll
        for (int j = 0; j < 8; ++j) acc[i][j] = 0.f;

    for (int k0 = 0; k0 < KPAD; k0 += GBK) {
        float4 av = make_float4(0.f, 0.f, 0.f, 0.f);
        const int ka = k0 + akq;
        if (ga < M && ka < DD) av = ld4(Aa + (size_t)ga * DD + ka);
        As[(akq + 0) * GBM + arow] = av.x;
        As[(akq + 1) * GBM + arow] = av.y;
        As[(akq + 2) * GBM + arow] = av.z;
        As[(akq + 3) * GBM + arow] = av.w;

        float4 bv = make_float4(0.f, 0.f, 0.f, 0.f);
        const int kb = k0 + brow;
        if (kb < DD && gb < DD) bv = ld4(Bw + (size_t)kb * DD + gb);
        *(float4*)(Bs + brow * GBN + bnq) = bv;

        __syncthreads();
#pragma unroll
        for (int kk = 0; kk < GBK; ++kk) {
            float a[8], b[8];
            *(float4*)&a[0] = *(const float4*)(As + kk * GBM + 8 * ty);
            *(float4*)&a[4] = *(const float4*)(As + kk * GBM + 8 * ty + 4);
            *(float4*)&b[0] = *(const float4*)(Bs + kk * GBN + 8 * tx);
            *(float4*)&b[4] = *(const float4*)(Bs + kk * GBN + 8 * tx + 4);
#pragma unroll
            for (int i = 0; i < 8; ++i)
#pragma unroll
                for (int j = 0; j < 8; ++j)
                    acc[i][j] = fmaf(a[i], b[j], acc[i][j]);
        }
        __syncthreads();
    }

#pragma unroll
    for (int i = 0; i < 8; ++i) {
        const int r = row0 + 8 * ty + i;
        if (r < M) {
#pragma unroll
            for (int jq = 0; jq < 2; ++jq) {
                const int c = col0 + 8 * tx + 4 * jq;
                if (c < DD) {
                    float4 bb = ld4(bias + c);
                    *(float4*)(C + (size_t)r * DD + c) = make_float4(
                        acc[i][4*jq+0] + bb.x, acc[i][4*jq+1] + bb.y,
                        acc[i][4*jq+2] + bb.z, acc[i][4*jq+3] + bb.w);
                }
            }
        }
    }
}

// ===========================================================================
// CSR build
// ===========================================================================
__global__ void deg_kernel(const int* __restrict__ dst, int* __restrict__ deg, int E)
{
    int e = blockIdx.x * 256 + threadIdx.x;
    if (e < E) atomicAdd(&deg[dst[e]], 1);
}

__global__ void scan1(const int* __restrict__ deg, int* __restrict__ out,
                      int* __restrict__ bsum, int n)
{
    __shared__ int sh[256];
    const int t = threadIdx.x;
    const int base = blockIdx.x * 1024 + t * 4;
    int v0 = (base + 0 < n) ? deg[base + 0] : 0;
    int v1 = (base + 1 < n) ? deg[base + 1] : 0;
    int v2 = (base + 2 < n) ? deg[base + 2] : 0;
    int v3 = (base + 3 < n) ? deg[base + 3] : 0;
    const int s = v0 + v1 + v2 + v3;
    sh[t] = s;
    __syncthreads();
    for (int off = 1; off < 256; off <<= 1) {
        int x = (t >= off) ? sh[t - off] : 0;
        __syncthreads();
        sh[t] += x;
        __syncthreads();
    }
    int ex = sh[t] - s;
    if (base + 0 < n) out[base + 0] = ex; ex += v0;
    if (base + 1 < n) out[base + 1] = ex; ex += v1;
    if (base + 2 < n) out[base + 2] = ex; ex += v2;
    if (base + 3 < n) out[base + 3] = ex;
    if (t == 255) bsum[blockIdx.x] = sh[255];
}

__global__ void scan2(int* __restrict__ bsum, int nb, int* __restrict__ offs, int n, int E)
{
    __shared__ int sh[256];
    const int t = threadIdx.x;
    const int v = (t < nb) ? bsum[t] : 0;
    sh[t] = v;
    __syncthreads();
    for (int off = 1; off < 256; off <<= 1) {
        int x = (t >= off) ? sh[t - off] : 0;
        __syncthreads();
        sh[t] += x;
        __syncthreads();
    }
    if (t < nb) bsum[t] = sh[t] - v;
    if (t == 0) offs[n] = E;
}

__global__ void scan3(int* __restrict__ offs, const int* __restrict__ bsum,
                      int* __restrict__ cursor, int n)
{
    int i = blockIdx.x * 256 + threadIdx.x;
    if (i < n) {
        int v = offs[i] + bsum[i >> 10];
        offs[i] = v;
        cursor[i] = v;
    }
}

__global__ void fill_kernel(const int* __restrict__ src, const int* __restrict__ dst,
                            int* __restrict__ cursor, int* __restrict__ esrc,
                            int* __restrict__ permpos, int E)
{
    int e = blockIdx.x * 256 + threadIdx.x;
    if (e < E) {
        int d = dst[e];
        int pos = atomicAdd(&cursor[d], 1);
        esrc[pos] = src[e];
        permpos[e] = pos;
    }
}

// ===========================================================================
// agg[i] = sum_in relu(h[src] + e[slot]);  4 nodes/block (1 wave each)
// ===========================================================================
__global__ void agg_kernel(const unsigned short* __restrict__ h,
                           const unsigned char* __restrict__ e,
                           const int* __restrict__ esrc, const int* __restrict__ offs,
                           unsigned short* __restrict__ agg, int N)
{
    const int node = blockIdx.x * 4 + (threadIdx.x >> 6);
    if (node >= N) return;
    const int lane = threadIdx.x & 63;
    const int beg = offs[node], end = offs[node + 1];
    for (int q = lane; q < 75; q += 64) {
        float4 s = make_float4(0.f, 0.f, 0.f, 0.f);
        for (int p = beg; p < end; ++p) {
            const int src = esrc[p];
            ushort4 hu = *(const ushort4*)(h + (size_t)src * DD + 4 * q);
            unsigned int eu = *(const unsigned int*)(e + (size_t)p * DD + 4 * q);
            s.x += fmaxf(bf2f(hu.x) + e42f((unsigned char)(eu & 0xFF)), 0.f);
            s.y += fmaxf(bf2f(hu.y) + e42f((unsigned char)((eu >> 8) & 0xFF)), 0.f);
            s.z += fmaxf(bf2f(hu.z) + e42f((unsigned char)((eu >> 16) & 0xFF)), 0.f);
            s.w += fmaxf(bf2f(hu.w) + e42f((unsigned char)(eu >> 24)), 0.f);
        }
        *(ushort4*)(agg + (size_t)node * DD + 4 * q) =
            make_ushort4(f2bf(s.x), f2bf(s.y), f2bf(s.z), f2bf(s.w));
    }
}

// ===========================================================================
// BatchNorm finalize (re-zeroes accumulators for the next layer) + apply
// ===========================================================================
__global__ void bn_fin(double* __restrict__ bnsum, double* __restrict__ bnsq,
                       const float* __restrict__ gamma, const float* __restrict__ beta,
                       float* __restrict__ scale, float* __restrict__ shift, double invN)
{
    const int c = threadIdx.x;
    if (c < DD) {
        double mu = bnsum[c] * invN;
        double var = bnsq[c] * invN - mu * mu;
        double inv = 1.0 / sqrt(var + 1e-5);
        double g = (double)gamma[c];
        scale[c] = (float)(g * inv);
        shift[c] = (float)((double)beta[c] - mu * inv * g);
        bnsum[c] = 0.0;
        bnsq[c]  = 0.0;
    }
}

__global__ void bn_apply(const unsigned short* __restrict__ h2,
                         const float* __restrict__ scale, const float* __restrict__ shift,
                         unsigned short* __restrict__ h, int total4)
{
    int idx = blockIdx.x * 256 + threadIdx.x;
    if (idx >= total4) return;
    int q = idx % 75;
    ushort4 v4 = ((const ushort4*)h2)[idx];
    float4 sc = ld4(scale + 4 * q);
    float4 sh = ld4(shift + 4 * q);
    float r0 = fmaxf(fmaf(bf2f(v4.x), sc.x, sh.x), 0.f);
    float r1 = fmaxf(fmaf(bf2f(v4.y), sc.y, sh.y), 0.f);
    float r2 = fmaxf(fmaf(bf2f(v4.z), sc.z, sh.z), 0.f);
    float r3 = fmaxf(fmaf(bf2f(v4.w), sc.w, sh.w), 0.f);
    ((ushort4*)h)[idx] = make_ushort4(f2bf(r0), f2bf(r1), f2bf(r2), f2bf(r3));
}

// ===========================================================================
// Per-graph mean pooling
// ===========================================================================
__global__ void pool_kernel(const unsigned short* __restrict__ h, const int* __restrict__ batch,
                            float* __restrict__ pooled, int N)
{
    const int g = blockIdx.x;
    __shared__ int sb[2];
    if (threadIdx.x == 0) {
        int lo = 0, hi = N;
        while (lo < hi) { int m = (lo + hi) >> 1; if (batch[m] < g) lo = m + 1; else hi = m; }
        sb[0] = lo;
        lo = 0; hi = N;
        while (lo < hi) { int m = (lo + hi) >> 1; if (batch[m] < g + 1) lo = m + 1; else hi = m; }
        sb[1] = lo;
    }
    __syncthreads();
    const int beg = sb[0], end = sb[1];
    const float cnt = (float)(end - beg);
    for (int d = threadIdx.x; d < DD; d += 256) {
        float s = 0.f;
        for (int i = beg; i < end; ++i) s += bf2f(h[(size_t)i * DD + d]);
        pooled[(size_t)g * DD + d] = (end > beg) ? (s / cnt) : 0.f;
    }
}

__global__ void diag_fill(float* __restrict__ out, int n, float v)
{
    int i = blockIdx.x * 256 + threadIdx.x;
    if (i < n) out[i] = v;
}

// ===========================================================================
extern "C" void kernel_launch(void* const* d_in, const int* in_sizes, int n_in,
                              void* d_out, int out_size, void* d_ws, size_t ws_size,
                              hipStream_t stream)
{
    const int N = in_sizes[0];
    const int E = in_sizes[3] / 2;
    const int G = out_size / DD;
    const int NPAD = (N + 127) & ~127;

    const int*   z     = (const int*)d_in[0];
    const float* chir  = (const float*)d_in[1];
    const float* fc    = (const float*)d_in[2];
    const int*   eidx  = (const int*)d_in[3];
    const float* eattr = (const float*)d_in[4];
    const int*   batch = (const int*)d_in[5];
    const float* aemb  = (const float*)d_in[7];
    const float* nW1   = (const float*)d_in[8];
    const float* nb1   = (const float*)d_in[9];
    const float* nW2   = (const float*)d_in[10];
    const float* nb2   = (const float*)d_in[11];
    const float* eW1   = (const float*)d_in[12];
    const float* eb1   = (const float*)d_in[13];
    const float* eW2   = (const float*)d_in[14];
    const float* eb2   = (const float*)d_in[15];
    const float* mW1   = (const float*)d_in[16];
    const float* mb1   = (const float*)d_in[17];
    const float* mW2   = (const float*)d_in[18];
    const float* mb2   = (const float*)d_in[19];
    const float* gamma = (const float*)d_in[20];
    const float* beta  = (const float*)d_in[21];
    const float* pW    = (const float*)d_in[22];
    const float* pb    = (const float*)d_in[23];
    float* out = (float*)d_out;

    size_t base = 0;
    auto A = [&](size_t b) -> size_t {
        size_t r = base; base += (b + 255) & ~(size_t)255; return r;
    };
    const size_t o_h    = A((size_t)NPAD * DD * 2 + 128); // h bf16, row-padded (DMA A1)
    const size_t o_t    = A((size_t)NPAD * DD * 2 + 128); // tbuf bf16, row-padded (DMA A)
    const size_t o_g    = A((size_t)NPAD * DD * 2 + 128); // agg / h2 bf16, row-padded (DMA A2)
    const size_t o_bns  = A(DD * 8);
    const size_t o_bnq  = A(DD * 8);
    const size_t o_scl  = A(DD * 4);
    const size_t o_shf  = A(DD * 4);
    const size_t o_offs = A((size_t)(N + 1) * 4);
    const size_t o_cur  = A((size_t)N * 4);
    const size_t o_bsum = A(1024 * 4);
    const size_t o_src  = A((size_t)E * 4);
    const size_t o_perm = A((size_t)E * 4);
    const size_t o_wt   = A((size_t)12 * 2 * WTR * KP * 2);  // 12 matrices, hi+lo
    const size_t o_e    = A((size_t)E * DD * 1);          // ebuf fp8, CSR-permuted
    const size_t need = base;

    if (ws_size < need) {
        diag_fill<<<(out_size + 255) / 256, 256, 0, stream>>>(
            out, out_size, 10000.f + (float)(ws_size >> 20));
        return;
    }

    char* w = (char*)d_ws;
    unsigned short* h      = (unsigned short*)(w + o_h);
    unsigned short* tbuf   = (unsigned short*)(w + o_t);
    unsigned short* aggh2  = (unsigned short*)(w + o_g);
    double*         bnsum  = (double*)(w + o_bns);
    double*         bnsq   = (double*)(w + o_bnq);
    float*          scl    = (float*)(w + o_scl);
    float*          shf    = (float*)(w + o_shf);
    int*            offs   = (int*)(w + o_offs);
    int*            cursor = (int*)(w + o_cur);
    int*            bsum   = (int*)(w + o_bsum);
    int*            esrc   = (int*)(w + o_src);
    int*            permpos= (int*)(w + o_perm);
    unsigned short* wt     = (unsigned short*)(w + o_wt);
    unsigned char*  ebuf   = (unsigned char*)(w + o_e);
    float*          pooled = (float*)tbuf;

    // weight slots: m=0 nW2, m=1 eW2, m=2+l mW1[l], m=7+l mW2[l]
    const size_t per = (size_t)WTR * KP;
    auto wHI = [&](int m) { return wt + (size_t)m * 2 * per; };
    auto wLO = [&](int m) { return wt + (size_t)m * 2 * per + per; };

    const int* srcI = eidx;
    const int* dstI = eidx + E;

    // ---- one-shot prep: weights + BN accumulator zero ----
    const int ptot = 12 * WTR * KP + DD;
    prep_all<<<(ptot + 255) / 256, 256, 0, stream>>>(nW2, eW2, mW1, mW2, wt, bnsum, bnsq);

    // ---- CSR of incoming edges ----
    hipMemsetAsync(cursor, 0, (size_t)N * 4, stream);
    deg_kernel<<<(E + 255) / 256, 256, 0, stream>>>(dstI, cursor, E);
    const int nb = (N + 1023) / 1024;
    scan1<<<nb, 256, 0, stream>>>(cursor, offs, bsum, N);
    scan2<<<1, 256, 0, stream>>>(bsum, nb, offs, N, E);
    scan3<<<(N + 255) / 256, 256, 0, stream>>>(offs, bsum, cursor, N);
    fill_kernel<<<(E + 255) / 256, 256, 0, stream>>>(srcI, dstI, cursor, esrc, permpos, E);

    const dim3 gN(3, (N + TM - 1) / TM);
    const dim3 gE(3, (E + TM - 1) / TM);
    const dim3 gG(3, (G + GBM - 1) / GBM);

    // ---- encoders (MFMA) ----
    mgemm<MA_NODE, ME_EMB><<<gN, 256, 0, stream>>>(
        (const unsigned short*)chir, (const unsigned short*)fc, wHI(0), wLO(0), nb2,
        nW1, nb1, z, aemb, nullptr, h, nullptr, nullptr, N);
    mgemm<MA_EDGE, ME_FP8><<<gE, 256, 0, stream>>>(
        (const unsigned short*)eattr, nullptr, wHI(1), wLO(1), eb2,
        eW1, eb1, nullptr, nullptr, permpos, ebuf, nullptr, nullptr, E);

    // ---- 5 GINE layers ----
    for (int l = 0; l < 5; ++l) {
        agg_kernel<<<(N + 3) / 4, 256, 0, stream>>>(h, ebuf, esrc, offs, aggh2, N);
        mgemm<MA_DMA2, ME_RELU><<<gN, 256, 0, stream>>>(
            h, aggh2, wHI(2 + l), wLO(2 + l), mb1 + l * DD,
            nullptr, nullptr, nullptr, nullptr, nullptr, tbuf, nullptr, nullptr, N);
        mgemm<MA_BF16, ME_BN><<<gN, 256, 0, stream>>>(
            tbuf, nullptr, wHI(7 + l), wLO(7 + l), mb2 + l * DD,
            nullptr, nullptr, nullptr, nullptr, nullptr, aggh2, bnsum, bnsq, N);
        bn_fin<<<1, 320, 0, stream>>>(bnsum, bnsq, gamma + l * DD, beta + l * DD,
                                      scl, shf, 1.0 / (double)N);
        const int tot4 = N * 75;
        bn_apply<<<(tot4 + 255) / 256, 256, 0, stream>>>(aggh2, scl, shf, h, tot4);
    }

    // ---- pooling + final projection ----
    pool_kernel<<<G, 256, 0, stream>>>(h, batch, pooled, N);
    gemm_final<<<gG, 256, 0, stream>>>(pooled, pW, pb, out, G);
}

// Round 11
// 2624.657 us; speedup vs baseline: 1.3927x; 1.0388x over previous
//
#include <hip/hip_runtime.h>

#define DD 300
#define KP 320    // padded K for pre-transposed weights
#define WTR 384   // weight rows padded (no guard needed in DMA staging)

typedef __attribute__((ext_vector_type(8))) short short8v;   // 8 bf16 = 4 VGPR
typedef __attribute__((ext_vector_type(4))) float f32x4;

__device__ __forceinline__ float4 ld4(const float* p) { return *(const float4*)p; }

__device__ __forceinline__ unsigned short f2bf(float f) {
    unsigned int u = __float_as_uint(f);
    unsigned int r = (u + 0x7fffu + ((u >> 16) & 1u)) >> 16;   // RNE
    return (unsigned short)r;
}
__device__ __forceinline__ float bf2f(unsigned short b) {
    return __uint_as_float(((unsigned int)b) << 16);
}

// async global->LDS, 16 B per lane; LDS dest = wave-uniform base + lane*16
__device__ __forceinline__ void gload16(const void* g, void* l) {
    __builtin_amdgcn_global_load_lds(
        (const __attribute__((address_space(1))) unsigned int*)g,
        (__attribute__((address_space(3))) unsigned int*)l, 16, 0, 0);
}

// ---- manual OCP e4m3fn -----------------------------------------------------
__device__ __forceinline__ unsigned char f2e4(float f) {
    unsigned int u = __float_as_uint(f);
    unsigned int s = (u >> 24) & 0x80u;
    float a = __uint_as_float(u & 0x7fffffffu);
    if (a >= 448.f) return (unsigned char)(s | 0x7Eu);
    if (a < 0x1p-10f) return (unsigned char)s;
    int e = (int)((__float_as_uint(a) >> 23) & 0xFF) - 127;
    int q = (e >= -6) ? (e - 3) : -9;
    float scale = __uint_as_float((unsigned int)(127 - q) << 23);
    int m = __float2int_rn(a * scale);
    if (e >= -6) {
        if (m == 16) { m = 8; e += 1; }
        return (unsigned char)(s | ((unsigned int)(e + 7) << 3) | (unsigned int)(m - 8));
    } else {
        if (m == 8) return (unsigned char)(s | (1u << 3));
        return (unsigned char)(s | (unsigned int)m);
    }
}
__device__ __forceinline__ float e42f(unsigned char b) {
    unsigned int s = ((unsigned int)(b & 0x80u)) << 24;
    unsigned int ef = (b >> 3) & 0xFu, mf = b & 7u;
    float mag = (ef == 0) ? ((float)mf) * 0x1p-9f
                          : __uint_as_float(((ef + 120u) << 23) | (mf << 20));
    return __uint_as_float(__float_as_uint(mag) | s);
}

// ===========================================================================
// One-shot prep: all 12 weight matrices -> transposed split bf16 hi/lo
// [WTR rows][KP], zero-padded; also zeroes the BN stat accumulators.
// ===========================================================================
__global__ void prep_all(const float* __restrict__ nW2, const float* __restrict__ eW2,
                         const float* __restrict__ mW1, const float* __restrict__ mW2,
                         unsigned short* __restrict__ wt,
                         double* __restrict__ bnsum, double* __restrict__ bnsq)
{
    const int per = WTR * KP;
    int id = blockIdx.x * 256 + threadIdx.x;
    if (id < 12 * per) {
        int m = id / per, r = id - m * per;
        int col = r / KP, k = r - col * KP;
        const float* W = (m == 0) ? nW2 : (m == 1) ? eW2
                       : (m < 7) ? (mW1 + (size_t)(m - 2) * DD * DD)
                                 : (mW2 + (size_t)(m - 7) * DD * DD);
        float v = (col < DD && k < DD) ? W[(size_t)k * DD + col] : 0.f;
        unsigned short h = f2bf(v);
        wt[(size_t)m * 2 * per + (size_t)col * KP + k] = h;
        wt[(size_t)m * 2 * per + per + (size_t)col * KP + k] = f2bf(v - bf2f(h));
    } else if (id < 12 * per + DD) {
        int c = id - 12 * per;
        bnsum[c] = 0.0; bnsq[c] = 0.0;
    }
}

// ===========================================================================
// MFMA split-bf16 GEMM:  C[M,300] = f(A @ B + bias)   TILE 256x128, 8 waves
// Modes:
//   MA_DMA2: A = Aa + Ab (both exact bf16), BOTH DMA-staged; 4 MFMA/fragpair
//   MA_BF16: A exact bf16, DMA-staged; 2 MFMA
//   MA_NODE: A on-the-fly (2 feats @ W1,relu), hi/lo split; 3 MFMA
//   MA_EDGE: A on-the-fly (3 feats @ W1,relu), HI ONLY (output is fp8;
//            fp8 quantization noise >> A-rounding); 2 MFMA
// B always pre-transposed/pre-split, DMA-staged.
// ===========================================================================
enum { MA_DMA2 = 0, MA_BF16 = 1, MA_NODE = 2, MA_EDGE = 3 };
enum { ME_RELU = 0, ME_BN = 1, ME_EMB = 2, ME_FP8 = 3 };

constexpr int TM = 256;
constexpr int TN = 128;
constexpr int TK = 32;
constexpr int KSTEPS = 10;   // 320 = KP

template<int AM, int EM>
__launch_bounds__(512)
__global__ void mgemm(const unsigned short* __restrict__ Aa,
                      const unsigned short* __restrict__ Ab,
                      const unsigned short* __restrict__ Bth,
                      const unsigned short* __restrict__ Btl,
                      const float* __restrict__ bias,
                      const float* __restrict__ W1,
                      const float* __restrict__ b1,
                      const int* __restrict__ zidx,
                      const float* __restrict__ emb,
                      const int* __restrict__ permpos,
                      void* __restrict__ Cv,
                      double* __restrict__ bnsum, double* __restrict__ bnsq,
                      int M)
{
    constexpr bool VSTAGE = (AM == MA_NODE || AM == MA_EDGE);
    constexpr bool ALO    = (AM == MA_NODE);      // lo path for VALU-staged A
    constexpr int  AP     = VSTAGE ? 40 : 32;
    __shared__ unsigned short sAh[TM * AP];
    __shared__ unsigned short sBh[TN * 32];
    __shared__ unsigned short sBl[TN * 32];
    __shared__ unsigned short sA2[(AM == MA_DMA2) ? TM * 32 : 64]; // agg tile (DMA)
    __shared__ unsigned short sAl[ALO ? TM * 40 : 64];             // lo tile (VALU)

    const int t    = threadIdx.x;
    const int col0 = blockIdx.x * TN;
    const int row0 = blockIdx.y * TM;
    const int lane = t & 63;
    const int wid  = t >> 6;              // 0..7
    const int wr   = wid >> 1;            // wave row (0..3, 64 rows each)
    const int wc   = wid & 1;             // wave col (0..1, 64 cols each)
    const int lr   = lane & 15;
    const int lk   = lane >> 4;           // 0..3

    // VALU staging assignment (512 threads cover 256 rows x 32 k)
    const int arow = t >> 1;              // 0..255
    const int akq  = (t & 1) * 16;        // 0 / 16 (k offset)
    // DMA staging assignment (16 rows x 64 B per instruction)
    const int dmarow = lane >> 2;         // 0..15
    const int dmakq  = (lane & 3) * 8;    // shorts: 0,8,16,24
    const int wbA  = wid * 32;            // A rows handled by this wave
    const int wbB  = wid * 16;            // B rows handled by this wave

    const int ga = row0 + arow;
    float f0 = 0.f, f1 = 0.f, f2 = 0.f;
    if (AM == MA_NODE && ga < M) {
        f0 = ((const float*)Aa)[ga]; f1 = ((const float*)Ab)[ga];
    }
    if (AM == MA_EDGE && ga < M) {
        const float* Af = (const float*)Aa;
        f0 = Af[(size_t)ga * 3 + 0];
        f1 = Af[(size_t)ga * 3 + 1];
        f2 = Af[(size_t)ga * 3 + 2];
    }

    f32x4 acc[4][4];
#pragma unroll
    for (int i = 0; i < 4; ++i)
#pragma unroll
        for (int j = 0; j < 4; ++j) acc[i][j] = (f32x4){0.f, 0.f, 0.f, 0.f};

    for (int ks = 0; ks < KSTEPS; ++ks) {
        const int k0 = ks * TK;
        __syncthreads();

        // ---- stage B via async DMA: 16 rows/wave/buffer
        gload16(Bth + (size_t)(col0 + wbB + dmarow) * KP + k0 + dmakq, &sBh[wbB * 32]);
        gload16(Btl + (size_t)(col0 + wbB + dmarow) * KP + k0 + dmakq, &sBl[wbB * 32]);

        // ---- stage A ----
        if (AM == MA_DMA2) {
            // both A operands exact bf16: pure DMA (pitch DD; k-spill rows
            // multiply zero-padded B rows k in [300,320) -> harmless)
#pragma unroll
            for (int i = 0; i < 2; ++i) {
                const int rb = wbA + i * 16;
                gload16(Aa + (size_t)(row0 + rb + dmarow) * DD + k0 + dmakq, &sAh[rb * 32]);
                gload16(Ab + (size_t)(row0 + rb + dmarow) * DD + k0 + dmakq, &sA2[rb * 32]);
            }
        } else if (AM == MA_BF16) {
#pragma unroll
            for (int i = 0; i < 2; ++i) {
                const int rb = wbA + i * 16;
                gload16(Aa + (size_t)(row0 + rb + dmarow) * DD + k0 + dmakq, &sAh[rb * 32]);
            }
        } else {
            float v[16];
#pragma unroll
            for (int q = 0; q < 4; ++q) {
                const int k = k0 + akq + q * 4;
                if (ga < M && k < DD) {
                    float4 w0 = ld4(W1 + k);
                    float4 w1 = ld4(W1 + DD + k);
                    float4 bb = ld4(b1 + k);
                    if (AM == MA_NODE) {
                        v[q*4+0] = fmaxf(fmaf(f0, w0.x, fmaf(f1, w1.x, bb.x)), 0.f);
                        v[q*4+1] = fmaxf(fmaf(f0, w0.y, fmaf(f1, w1.y, bb.y)), 0.f);
                        v[q*4+2] = fmaxf(fmaf(f0, w0.z, fmaf(f1, w1.z, bb.z)), 0.f);
                        v[q*4+3] = fmaxf(fmaf(f0, w0.w, fmaf(f1, w1.w, bb.w)), 0.f);
                    } else {
                        float4 w2 = ld4(W1 + 2 * DD + k);
                        v[q*4+0] = fmaxf(f0*w0.x + f1*w1.x + f2*w2.x + bb.x, 0.f);
                        v[q*4+1] = fmaxf(f0*w0.y + f1*w1.y + f2*w2.y + bb.y, 0.f);
                        v[q*4+2] = fmaxf(f0*w0.z + f1*w1.z + f2*w2.z + bb.z, 0.f);
                        v[q*4+3] = fmaxf(f0*w0.w + f1*w1.w + f2*w2.w + bb.w, 0.f);
                    }
                } else {
                    v[q*4+0] = v[q*4+1] = v[q*4+2] = v[q*4+3] = 0.f;
                }
            }
#pragma unroll
            for (int q = 0; q < 4; ++q) {
                ushort4 hi;
                hi.x = f2bf(v[q*4+0]);
                hi.y = f2bf(v[q*4+1]);
                hi.z = f2bf(v[q*4+2]);
                hi.w = f2bf(v[q*4+3]);
                *(ushort4*)&sAh[arow * AP + akq + q * 4] = hi;
                if constexpr (ALO) {
                    ushort4 lo;
                    lo.x = f2bf(v[q*4+0] - bf2f(hi.x));
                    lo.y = f2bf(v[q*4+1] - bf2f(hi.y));
                    lo.z = f2bf(v[q*4+2] - bf2f(hi.z));
                    lo.w = f2bf(v[q*4+3] - bf2f(hi.w));
                    *(ushort4*)&sAl[arow * 40 + akq + q * 4] = lo;
                }
            }
        }
        __syncthreads();   // compiler drains vmcnt (DMA) + lgkm before barrier

        // ---- fragments + MFMA ----
        short8v aH[4], aX[4], bH[4], bL[4];
#pragma unroll
        for (int f = 0; f < 4; ++f) {
            aH[f] = *(const short8v*)&sAh[(wr * 64 + f * 16 + lr) * AP + lk * 8];
            bH[f] = *(const short8v*)&sBh[(wc * 64 + f * 16 + lr) * 32 + lk * 8];
            bL[f] = *(const short8v*)&sBl[(wc * 64 + f * 16 + lr) * 32 + lk * 8];
            if constexpr (AM == MA_DMA2)
                aX[f] = *(const short8v*)&sA2[(wr * 64 + f * 16 + lr) * 32 + lk * 8];
            if constexpr (ALO)
                aX[f] = *(const short8v*)&sAl[(wr * 64 + f * 16 + lr) * 40 + lk * 8];
        }
#pragma unroll
        for (int fi = 0; fi < 4; ++fi)
#pragma unroll
            for (int fj = 0; fj < 4; ++fj) {
                acc[fi][fj] = __builtin_amdgcn_mfma_f32_16x16x32_bf16(aH[fi], bH[fj], acc[fi][fj], 0, 0, 0);
                acc[fi][fj] = __builtin_amdgcn_mfma_f32_16x16x32_bf16(aH[fi], bL[fj], acc[fi][fj], 0, 0, 0);
                if constexpr (AM == MA_DMA2) {
                    acc[fi][fj] = __builtin_amdgcn_mfma_f32_16x16x32_bf16(aX[fi], bH[fj], acc[fi][fj], 0, 0, 0);
                    acc[fi][fj] = __builtin_amdgcn_mfma_f32_16x16x32_bf16(aX[fi], bL[fj], acc[fi][fj], 0, 0, 0);
                }
                if constexpr (ALO)
                    acc[fi][fj] = __builtin_amdgcn_mfma_f32_16x16x32_bf16(aX[fi], bH[fj], acc[fi][fj], 0, 0, 0);
            }
    }

    // ---- epilogue: C row = row0+wr*64+fi*16+lk*4+i, col = col0+wc*64+fj*16+lr
    float csum[4], csq[4];
#pragma unroll
    for (int j = 0; j < 4; ++j) { csum[j] = 0.f; csq[j] = 0.f; }

#pragma unroll
    for (int fi = 0; fi < 4; ++fi) {
#pragma unroll
        for (int i = 0; i < 4; ++i) {
            const int r = row0 + wr * 64 + fi * 16 + lk * 4 + i;
            if (r < M) {
                int zr = 0, pr = 0;
                if (EM == ME_EMB) zr = zidx[r];
                if (EM == ME_FP8) pr = permpos[r];
#pragma unroll
                for (int fj = 0; fj < 4; ++fj) {
                    const int c = col0 + wc * 64 + fj * 16 + lr;
                    if (c < DD) {
                        float v = acc[fi][fj][i] + bias[c];
                        if (EM == ME_RELU) v = fmaxf(v, 0.f);
                        if (EM == ME_EMB)  v += emb[(size_t)zr * DD + c];
                        if (EM == ME_FP8)
                            ((unsigned char*)Cv)[(size_t)pr * DD + c] = f2e4(v);
                        else
                            ((unsigned short*)Cv)[(size_t)r * DD + c] = f2bf(v);
                        if (EM == ME_BN) { csum[fj] += v; csq[fj] += v * v; }
                    }
                }
            }
        }
    }

    if (EM == ME_BN) {
        // Per-column stats: shuffle-reduce lanes {l,l^16,l^32,l^48}, then
        // combine the 4 wave-rows via sRed[4][TN] (row=wr, col=wc*64+fj*16+lr).
        // Waves (wr,0),(wr,1) tile row wr disjointly -> full coverage.
#pragma unroll
        for (int fj = 0; fj < 4; ++fj) {
            csum[fj] += __shfl_xor(csum[fj], 16);
            csum[fj] += __shfl_xor(csum[fj], 32);
            csq[fj]  += __shfl_xor(csq[fj], 16);
            csq[fj]  += __shfl_xor(csq[fj], 32);
        }
        float* sRed = (float*)sAh;   // 4*128 floats, tiles are dead
        __syncthreads();
        if (lk == 0) {
#pragma unroll
            for (int fj = 0; fj < 4; ++fj)
                sRed[wr * TN + wc * 64 + fj * 16 + lr] = csum[fj];
        }
        __syncthreads();
        if (t < TN) {
            float s = sRed[t] + sRed[TN + t] + sRed[2 * TN + t] + sRed[3 * TN + t];
            const int c = col0 + t;
            if (c < DD) unsafeAtomicAdd(&bnsum[c], (double)s);
        }
        __syncthreads();
        if (lk == 0) {
#pragma unroll
            for (int fj = 0; fj < 4; ++fj)
                sRed[wr * TN + wc * 64 + fj * 16 + lr] = csq[fj];
        }
        __syncthreads();
        if (t < TN) {
            float s = sRed[t] + sRed[TN + t] + sRed[2 * TN + t] + sRed[3 * TN + t];
            const int c = col0 + t;
            if (c < DD) unsafeAtomicAdd(&bnsq[c], (double)s);
        }
    }
}

// ===========================================================================
// fp32 VALU GEMM kept only for the tiny final projection (G=4096)
// ===========================================================================
constexpr int GBM = 128;
constexpr int GBN = 128;
constexpr int GBK = 8;
constexpr int KPAD = 304;

__launch_bounds__(256)
__global__ void gemm_final(const float* __restrict__ Aa, const float* __restrict__ Bw,
                           const float* __restrict__ bias, float* __restrict__ C, int M)
{
    __shared__ float smem[2 * GBK * GBM];
    float* As = smem;
    float* Bs = smem + GBK * GBM;

    const int t    = threadIdx.x;
    const int tx   = t & 15;
    const int ty   = t >> 4;
    const int col0 = blockIdx.x * GBN;
    const int row0 = blockIdx.y * GBM;
    const int arow = t >> 1;
    const int akq  = (t & 1) << 2;
    const int brow = t >> 5;
    const int bnq  = (t & 31) << 2;
    const int ga   = row0 + arow;
    const int gb   = col0 + bnq;

    float acc[8][8];
#pragma unroll
    for (int i = 0; i < 8; ++i)
#pragma unroll
        for (int j = 0; j < 8; ++j) acc[i][j] = 0.f;

    for (int k0 = 0; k0 < KPAD; k0 += GBK) {
        float4 av = make_float4(0.f, 0.f, 0.f, 0.f);
        const int ka = k0 + akq;
        if (ga < M && ka < DD) av = ld4(Aa + (size_t)ga * DD + ka);
        As[(akq + 0) * GBM + arow] = av.x;
        As[(akq + 1) * GBM + arow] = av.y;
        As[(akq + 2) * GBM + arow] = av.z;
        As[(akq + 3) * GBM + arow] = av.w;

        float4 bv = make_float4(0.f, 0.f, 0.f, 0.f);
        const int kb = k0 + brow;
        if (kb < DD && gb < DD) bv = ld4(Bw + (size_t)kb * DD + gb);
        *(float4*)(Bs + brow * GBN + bnq) = bv;

        __syncthreads();
#pragma unroll
        for (int kk = 0; kk < GBK; ++kk) {
            float a[8], b[8];
            *(float4*)&a[0] = *(const float4*)(As + kk * GBM + 8 * ty);
            *(float4*)&a[4] = *(const float4*)(As + kk * GBM + 8 * ty + 4);
            *(float4*)&b[0] = *(const float4*)(Bs + kk * GBN + 8 * tx);
            *(float4*)&b[4] = *(const float4*)(Bs + kk * GBN + 8 * tx + 4);
#pragma unroll
            for (int i = 0; i < 8; ++i)
#pragma unroll
                for (int j = 0; j < 8; ++j)
                    acc[i][j] = fmaf(a[i], b[j], acc[i][j]);
        }
        __syncthreads();
    }

#pragma unroll
    for (int i = 0; i < 8; ++i) {
        const int r = row0 + 8 * ty + i;
        if (r < M) {
#pragma unroll
            for (int jq = 0; jq < 2; ++jq) {
                const int c = col0 + 8 * tx + 4 * jq;
                if (c < DD) {
                    float4 bb = ld4(bias + c);
                    *(float4*)(C + (size_t)r * DD + c) = make_float4(
                        acc[i][4*jq+0] + bb.x, acc[i][4*jq+1] + bb.y,
                        acc[i][4*jq+2] + bb.z, acc[i][4*jq+3] + bb.w);
                }
            }
        }
    }
}

// ===========================================================================
// CSR build
// ===========================================================================
__global__ void deg_kernel(const int* __restrict__ dst, int* __restrict__ deg, int E)
{
    int e = blockIdx.x * 256 + threadIdx.x;
    if (e < E) atomicAdd(&deg[dst[e]], 1);
}

__global__ void scan1(const int* __restrict__ deg, int* __restrict__ out,
                      int* __restrict__ bsum, int n)
{
    __shared__ int sh[256];
    const int t = threadIdx.x;
    const int base = blockIdx.x * 1024 + t * 4;
    int v0 = (base + 0 < n) ? deg[base + 0] : 0;
    int v1 = (base + 1 < n) ? deg[base + 1] : 0;
    int v2 = (base + 2 < n) ? deg[base + 2] : 0;
    int v3 = (base + 3 < n) ? deg[base + 3] : 0;
    const int s = v0 + v1 + v2 + v3;
    sh[t] = s;
    __syncthreads();
    for (int off = 1; off < 256; off <<= 1) {
        int x = (t >= off) ? sh[t - off] : 0;
        __syncthreads();
        sh[t] += x;
        __syncthreads();
    }
    int ex = sh[t] - s;
    if (base + 0 < n) out[base + 0] = ex; ex += v0;
    if (base + 1 < n) out[base + 1] = ex; ex += v1;
    if (base + 2 < n) out[base + 2] = ex; ex += v2;
    if (base + 3 < n) out[base + 3] = ex;
    if (t == 255) bsum[blockIdx.x] = sh[255];
}

__global__ void scan2(int* __restrict__ bsum, int nb, int* __restrict__ offs, int n, int E)
{
    __shared__ int sh[256];
    const int t = threadIdx.x;
    const int v = (t < nb) ? bsum[t] : 0;
    sh[t] = v;
    __syncthreads();
    for (int off = 1; off < 256; off <<= 1) {
        int x = (t >= off) ? sh[t - off] : 0;
        __syncthreads();
        sh[t] += x;
        __syncthreads();
    }
    if (t < nb) bsum[t] = sh[t] - v;
    if (t == 0) offs[n] = E;
}

__global__ void scan3(int* __restrict__ offs, const int* __restrict__ bsum,
                      int* __restrict__ cursor, int n)
{
    int i = blockIdx.x * 256 + threadIdx.x;
    if (i < n) {
        int v = offs[i] + bsum[i >> 10];
        offs[i] = v;
        cursor[i] = v;
    }
}

__global__ void fill_kernel(const int* __restrict__ src, const int* __restrict__ dst,
                            int* __restrict__ cursor, int* __restrict__ esrc,
                            int* __restrict__ permpos, int E)
{
    int e = blockIdx.x * 256 + threadIdx.x;
    if (e < E) {
        int d = dst[e];
        int pos = atomicAdd(&cursor[d], 1);
        esrc[pos] = src[e];
        permpos[e] = pos;
    }
}

// ===========================================================================
// agg[i] = sum_in relu(h[src] + e[slot]);  4 nodes/block (1 wave each)
// ===========================================================================
__global__ void agg_kernel(const unsigned short* __restrict__ h,
                           const unsigned char* __restrict__ e,
                           const int* __restrict__ esrc, const int* __restrict__ offs,
                           unsigned short* __restrict__ agg, int N)
{
    const int node = blockIdx.x * 4 + (threadIdx.x >> 6);
    if (node >= N) return;
    const int lane = threadIdx.x & 63;
    const int beg = offs[node], end = offs[node + 1];
    for (int q = lane; q < 75; q += 64) {
        float4 s = make_float4(0.f, 0.f, 0.f, 0.f);
        for (int p = beg; p < end; ++p) {
            const int src = esrc[p];
            ushort4 hu = *(const ushort4*)(h + (size_t)src * DD + 4 * q);
            unsigned int eu = *(const unsigned int*)(e + (size_t)p * DD + 4 * q);
            s.x += fmaxf(bf2f(hu.x) + e42f((unsigned char)(eu & 0xFF)), 0.f);
            s.y += fmaxf(bf2f(hu.y) + e42f((unsigned char)((eu >> 8) & 0xFF)), 0.f);
            s.z += fmaxf(bf2f(hu.z) + e42f((unsigned char)((eu >> 16) & 0xFF)), 0.f);
            s.w += fmaxf(bf2f(hu.w) + e42f((unsigned char)(eu >> 24)), 0.f);
        }
        *(ushort4*)(agg + (size_t)node * DD + 4 * q) =
            make_ushort4(f2bf(s.x), f2bf(s.y), f2bf(s.z), f2bf(s.w));
    }
}

// ===========================================================================
// BatchNorm finalize (re-zeroes accumulators for the next layer) + apply
// ===========================================================================
__global__ void bn_fin(double* __restrict__ bnsum, double* __restrict__ bnsq,
                       const float* __restrict__ gamma, const float* __restrict__ beta,
                       float* __restrict__ scale, float* __restrict__ shift, double invN)
{
    const int c = threadIdx.x;
    if (c < DD) {
        double mu = bnsum[c] * invN;
        double var = bnsq[c] * invN - mu * mu;
        double inv = 1.0 / sqrt(var + 1e-5);
        double g = (double)gamma[c];
        scale[c] = (float)(g * inv);
        shift[c] = (float)((double)beta[c] - mu * inv * g);
        bnsum[c] = 0.0;
        bnsq[c]  = 0.0;
    }
}

__global__ void bn_apply(const unsigned short* __restrict__ h2,
                         const float* __restrict__ scale, const float* __restrict__ shift,
                         unsigned short* __restrict__ h, int total4)
{
    int idx = blockIdx.x * 256 + threadIdx.x;
    if (idx >= total4) return;
    int q = idx % 75;
    ushort4 v4 = ((const ushort4*)h2)[idx];
    float4 sc = ld4(scale + 4 * q);
    float4 sh = ld4(shift + 4 * q);
    float r0 = fmaxf(fmaf(bf2f(v4.x), sc.x, sh.x), 0.f);
    float r1 = fmaxf(fmaf(bf2f(v4.y), sc.y, sh.y), 0.f);
    float r2 = fmaxf(fmaf(bf2f(v4.z), sc.z, sh.z), 0.f);
    float r3 = fmaxf(fmaf(bf2f(v4.w), sc.w, sh.w), 0.f);
    ((ushort4*)h)[idx] = make_ushort4(f2bf(r0), f2bf(r1), f2bf(r2), f2bf(r3));
}

// ===========================================================================
// Per-graph mean pooling
// ===========================================================================
__global__ void pool_kernel(const unsigned short* __restrict__ h, const int* __restrict__ batch,
                            float* __restrict__ pooled, int N)
{
    const int g = blockIdx.x;
    __shared__ int sb[2];
    if (threadIdx.x == 0) {
        int lo = 0, hi = N;
        while (lo < hi) { int m = (lo + hi) >> 1; if (batch[m] < g) lo = m + 1; else hi = m; }
        sb[0] = lo;
        lo = 0; hi = N;
        while (lo < hi) { int m = (lo + hi) >> 1; if (batch[m] < g + 1) lo = m + 1; else hi = m; }
        sb[1] = lo;
    }
    __syncthreads();
    const int beg = sb[0], end = sb[1];
    const float cnt = (float)(end - beg);
    for (int d = threadIdx.x; d < DD; d += 256) {
        float s = 0.f;
        for (int i = beg; i < end; ++i) s += bf2f(h[(size_t)i * DD + d]);
        pooled[(size_t)g * DD + d] = (end > beg) ? (s / cnt) : 0.f;
    }
}

__global__ void diag_fill(float* __restrict__ out, int n, float v)
{
    int i = blockIdx.x * 256 + threadIdx.x;
    if (i < n) out[i] = v;
}

// ===========================================================================
extern "C" void kernel_launch(void* const* d_in, const int* in_sizes, int n_in,
                              void* d_out, int out_size, void* d_ws, size_t ws_size,
                              hipStream_t stream)
{
    const int N = in_sizes[0];
    const int E = in_sizes[3] / 2;
    const int G = out_size / DD;
    const int NPAD = (N + 255) & ~255;

    const int*   z     = (const int*)d_in[0];
    const float* chir  = (const float*)d_in[1];
    const float* fc    = (const float*)d_in[2];
    const int*   eidx  = (const int*)d_in[3];
    const float* eattr = (const float*)d_in[4];
    const int*   batch = (const int*)d_in[5];
    const float* aemb  = (const float*)d_in[7];
    const float* nW1   = (const float*)d_in[8];
    const float* nb1   = (const float*)d_in[9];
    const float* nW2   = (const float*)d_in[10];
    const float* nb2   = (const float*)d_in[11];
    const float* eW1   = (const float*)d_in[12];
    const float* eb1   = (const float*)d_in[13];
    const float* eW2   = (const float*)d_in[14];
    const float* eb2   = (const float*)d_in[15];
    const float* mW1   = (const float*)d_in[16];
    const float* mb1   = (const float*)d_in[17];
    const float* mW2   = (const float*)d_in[18];
    const float* mb2   = (const float*)d_in[19];
    const float* gamma = (const float*)d_in[20];
    const float* beta  = (const float*)d_in[21];
    const float* pW    = (const float*)d_in[22];
    const float* pb    = (const float*)d_in[23];
    float* out = (float*)d_out;

    size_t base = 0;
    auto A = [&](size_t b) -> size_t {
        size_t r = base; base += (b + 255) & ~(size_t)255; return r;
    };
    const size_t o_h    = A((size_t)NPAD * DD * 2 + 128); // h bf16, row-padded (DMA)
    const size_t o_t    = A((size_t)NPAD * DD * 2 + 128); // tbuf bf16, row-padded (DMA)
    const size_t o_g    = A((size_t)NPAD * DD * 2 + 128); // agg/h2 bf16, row-padded (DMA)
    const size_t o_bns  = A(DD * 8);
    const size_t o_bnq  = A(DD * 8);
    const size_t o_scl  = A(DD * 4);
    const size_t o_shf  = A(DD * 4);
    const size_t o_offs = A((size_t)(N + 1) * 4);
    const size_t o_cur  = A((size_t)N * 4);
    const size_t o_bsum = A(1024 * 4);
    const size_t o_src  = A((size_t)E * 4);
    const size_t o_perm = A((size_t)E * 4);
    const size_t o_wt   = A((size_t)12 * 2 * WTR * KP * 2);  // 12 matrices, hi+lo
    const size_t o_e    = A((size_t)E * DD * 1);          // ebuf fp8, CSR-permuted
    const size_t need = base;

    if (ws_size < need) {
        diag_fill<<<(out_size + 255) / 256, 256, 0, stream>>>(
            out, out_size, 10000.f + (float)(ws_size >> 20));
        return;
    }

    char* w = (char*)d_ws;
    unsigned short* h      = (unsigned short*)(w + o_h);
    unsigned short* tbuf   = (unsigned short*)(w + o_t);
    unsigned short* aggh2  = (unsigned short*)(w + o_g);
    double*         bnsum  = (double*)(w + o_bns);
    double*         bnsq   = (double*)(w + o_bnq);
    float*          scl    = (float*)(w + o_scl);
    float*          shf    = (float*)(w + o_shf);
    int*            offs   = (int*)(w + o_offs);
    int*            cursor = (int*)(w + o_cur);
    int*            bsum   = (int*)(w + o_bsum);
    int*            esrc   = (int*)(w + o_src);
    int*            permpos= (int*)(w + o_perm);
    unsigned short* wt     = (unsigned short*)(w + o_wt);
    unsigned char*  ebuf   = (unsigned char*)(w + o_e);
    float*          pooled = (float*)tbuf;

    // weight slots: m=0 nW2, m=1 eW2, m=2+l mW1[l], m=7+l mW2[l]
    const size_t per = (size_t)WTR * KP;
    auto wHI = [&](int m) { return wt + (size_t)m * 2 * per; };
    auto wLO = [&](int m) { return wt + (size_t)m * 2 * per + per; };

    const int* srcI = eidx;
    const int* dstI = eidx + E;

    // ---- one-shot prep: weights + BN accumulator zero ----
    const int ptot = 12 * WTR * KP + DD;
    prep_all<<<(ptot + 255) / 256, 256, 0, stream>>>(nW2, eW2, mW1, mW2, wt, bnsum, bnsq);

    // ---- CSR of incoming edges ----
    hipMemsetAsync(cursor, 0, (size_t)N * 4, stream);
    deg_kernel<<<(E + 255) / 256, 256, 0, stream>>>(dstI, cursor, E);
    const int nb = (N + 1023) / 1024;
    scan1<<<nb, 256, 0, stream>>>(cursor, offs, bsum, N);
    scan2<<<1, 256, 0, stream>>>(bsum, nb, offs, N, E);
    scan3<<<(N + 255) / 256, 256, 0, stream>>>(offs, bsum, cursor, N);
    fill_kernel<<<(E + 255) / 256, 256, 0, stream>>>(srcI, dstI, cursor, esrc, permpos, E);

    const dim3 gN(3, (N + TM - 1) / TM);
    const dim3 gE(3, (E + TM - 1) / TM);
    const dim3 gG(3, (G + GBM - 1) / GBM);

    // ---- encoders (MFMA) ----
    mgemm<MA_NODE, ME_EMB><<<gN, 512, 0, stream>>>(
        (const unsigned short*)chir, (const unsigned short*)fc, wHI(0), wLO(0), nb2,
        nW1, nb1, z, aemb, nullptr, h, nullptr, nullptr, N);
    mgemm<MA_EDGE, ME_FP8><<<gE, 512, 0, stream>>>(
        (const unsigned short*)eattr, nullptr, wHI(1), wLO(1), eb2,
        eW1, eb1, nullptr, nullptr, permpos, ebuf, nullptr, nullptr, E);

    // ---- 5 GINE layers ----
    for (int l = 0; l < 5; ++l) {
        agg_kernel<<<(N + 3) / 4, 256, 0, stream>>>(h, ebuf, esrc, offs, aggh2, N);
        mgemm<MA_DMA2, ME_RELU><<<gN, 512, 0, stream>>>(
            h, aggh2, wHI(2 + l), wLO(2 + l), mb1 + l * DD,
            nullptr, nullptr, nullptr, nullptr, nullptr, tbuf, nullptr, nullptr, N);
        mgemm<MA_BF16, ME_BN><<<gN, 512, 0, stream>>>(
            tbuf, nullptr, wHI(7 + l), wLO(7 + l), mb2 + l * DD,
            nullptr, nullptr, nullptr, nullptr, nullptr, aggh2, bnsum, bnsq, N);
        bn_fin<<<1, 320, 0, stream>>>(bnsum, bnsq, gamma + l * DD, beta + l * DD,
                                      scl, shf, 1.0 / (double)N);
        const int tot4 = N * 75;
        bn_apply<<<(tot4 + 255) / 256, 256, 0, stream>>>(aggh2, scl, shf, h, tot4);
    }

    // ---- pooling + final projection ----
    pool_kernel<<<G, 256, 0, stream>>>(h, batch, pooled, N);
    gemm_final<<<gG, 256, 0, stream>>>(pooled, pW, pb, out, G);
}